// Round 11
// baseline (769.602 us; speedup 1.0000x reference)
//
#include <hip/hip_runtime.h>
#include <math.h>

#define B_ 4
#define N_ 20000
#define E_ 100000
#define C_ 128
#define K_ 32
#define NPAD 20480   // padded node count (multiple of 64)
#define NROWS (B_*N_ + 128)   // row slack so unguarded tile reads stay in-bounds

typedef __attribute__((ext_vector_type(8))) short short8;
typedef __attribute__((ext_vector_type(4))) float floatx4;
typedef __attribute__((ext_vector_type(4))) unsigned int uintx4;
typedef __attribute__((ext_vector_type(2))) unsigned int uintx2;

__device__ __forceinline__ float gelu_exact(float x){
    return 0.5f * x * (1.0f + erff(x * 0.70710678118654752f));
}

__device__ __forceinline__ unsigned short f2bf(float f){
    unsigned int u = __builtin_bit_cast(unsigned int, f);
    u += 0x7FFFu + ((u >> 16) & 1u);   // RNE
    return (unsigned short)(u >> 16);
}
__device__ __forceinline__ unsigned int pack2(float a, float b){
    return (unsigned int)f2bf(a) | ((unsigned int)f2bf(b) << 16);
}
__device__ __forceinline__ float bf2f(unsigned short u){
    unsigned int v = ((unsigned int)u) << 16;
    return __builtin_bit_cast(float, v);
}

// ---------------- setup: basis ----------------

__global__ __launch_bounds__(256) void basis_kernel(
    const float* __restrict__ nodes, const float* __restrict__ nw,
    const float* __restrict__ modes, const float* __restrict__ latent,
    unsigned short* __restrict__ bcb, unsigned short* __restrict__ bsb,
    unsigned short* __restrict__ wBt)
{
    __shared__ float lx[64], ly[64], lz[64], lwv[64];
    __shared__ unsigned short lTc[32*64], lTs[32*64];
    int b = blockIdx.y, n0 = blockIdx.x*64;
    int tid = threadIdx.x;
    size_t bN = (size_t)b*N_;
    if (tid < 64){
        int n = n0 + tid;
        float iL0 = 0.5f + 1.5f/(1.f+expf(-latent[0]));
        float iL1 = 0.5f + 1.5f/(1.f+expf(-latent[1]));
        float iL2 = 0.5f + 1.5f/(1.f+expf(-latent[2]));
        if (n < N_){
            lx[tid] = nodes[(bN+n)*3+0]*iL0;
            ly[tid] = nodes[(bN+n)*3+1]*iL1;
            lz[tid] = nodes[(bN+n)*3+2]*iL2;
            lwv[tid] = nw[bN+n];
        } else { lx[tid]=0.f; ly[tid]=0.f; lz[tid]=0.f; lwv[tid]=0.f; }
    }
    __syncthreads();
    int node = tid>>2, k0 = (tid&3)*8;
    float p0 = lx[node], p1 = ly[node], p2 = lz[node], w = lwv[node];
    float cv[8], sv[8];
    #pragma unroll
    for (int i=0;i<8;i++){
        int k = k0+i;
        float t = p0*modes[k*3+0] + p1*modes[k*3+1] + p2*modes[k*3+2];
        cv[i] = cosf(t); sv[i] = sinf(t);
        lTc[k*64 + node] = f2bf(w*cv[i]);
        lTs[k*64 + node] = f2bf(w*sv[i]);
    }
    int gn = n0 + node;
    if (gn < N_){
        uintx4 uc = (uintx4){pack2(cv[0],cv[1]), pack2(cv[2],cv[3]),
                             pack2(cv[4],cv[5]), pack2(cv[6],cv[7])};
        uintx4 us = (uintx4){pack2(sv[0],sv[1]), pack2(sv[2],sv[3]),
                             pack2(sv[4],sv[5]), pack2(sv[6],sv[7])};
        *(uintx4*)&bcb[(bN+gn)*K_ + k0] = uc;
        *(uintx4*)&bsb[(bN+gn)*K_ + k0] = us;
    }
    __syncthreads();
    #pragma unroll
    for (int i=0;i<5;i++){
        int idx = i*256 + tid;   // < 1280
        int row = idx>>4, seg = idx&15;
        unsigned short v0,v1,v2,v3;
        if (row < 32){
            v0=lTc[row*64+seg*4+0]; v1=lTc[row*64+seg*4+1];
            v2=lTc[row*64+seg*4+2]; v3=lTc[row*64+seg*4+3];
        } else if (row < 64){
            int r = row-32;
            v0=lTs[r*64+seg*4+0]; v1=lTs[r*64+seg*4+1];
            v2=lTs[r*64+seg*4+2]; v3=lTs[r*64+seg*4+3];
        } else if (row == 64){
            v0=f2bf(lwv[seg*4+0]); v1=f2bf(lwv[seg*4+1]);
            v2=f2bf(lwv[seg*4+2]); v3=f2bf(lwv[seg*4+3]);
        } else { v0=v1=v2=v3=0; }
        uintx2 u;
        u.x = (unsigned int)v0 | ((unsigned int)v1<<16);
        u.y = (unsigned int)v2 | ((unsigned int)v3<<16);
        *(uintx2*)&wBt[((size_t)b*80+row)*NPAD + n0 + seg*4] = u;
    }
}

// ---------------- setup: fc0 ----------------

__global__ __launch_bounds__(256) void fc0_kernel(
    const float* __restrict__ x, const float* __restrict__ w,
    const float* __restrict__ bvec, unsigned short* __restrict__ hN,
    unsigned short* __restrict__ hT)
{
    int idx = blockIdx.x*256 + threadIdx.x;
    if (idx >= B_*N_) return;
    int b = idx / N_, n = idx - b*N_;
    float x0 = x[(size_t)idx*3+0], x1 = x[(size_t)idx*3+1], x2 = x[(size_t)idx*3+2];
    unsigned short* hr = hN + (size_t)idx*C_;
    for (int c=0;c<C_;c+=4){
        float4 v;
        v.x = bvec[c+0] + x0*w[(c+0)*3] + x1*w[(c+0)*3+1] + x2*w[(c+0)*3+2];
        v.y = bvec[c+1] + x0*w[(c+1)*3] + x1*w[(c+1)*3+1] + x2*w[(c+1)*3+2];
        v.z = bvec[c+2] + x0*w[(c+2)*3] + x1*w[(c+2)*3+1] + x2*w[(c+2)*3+2];
        v.w = bvec[c+3] + x0*w[(c+3)*3] + x1*w[(c+3)*3+1] + x2*w[(c+3)*3+2];
        uintx2 u; u.x = pack2(v.x,v.y); u.y = pack2(v.z,v.w);
        *(uintx2*)(hr+c) = u;
        hT[((size_t)b*C_+c+0)*NPAD + n] = f2bf(v.x);
        hT[((size_t)b*C_+c+1)*NPAD + n] = f2bf(v.y);
        hT[((size_t)b*C_+c+2)*NPAD + n] = f2bf(v.z);
        hT[((size_t)b*C_+c+3)*NPAD + n] = f2bf(v.w);
    }
}

// ---------------- CSR build ----------------

__global__ __launch_bounds__(256) void hist_kernel(
    const int* __restrict__ edges, int* __restrict__ cnt)
{
    int idx = blockIdx.x*256 + threadIdx.x;
    if (idx >= B_*E_) return;
    int b = idx / E_;
    int t = edges[(size_t)idx*2];
    atomicAdd(cnt + b*N_ + t, 1);
}

__global__ __launch_bounds__(1024) void scan_kernel(
    const int* __restrict__ cnt, int* __restrict__ rowptr, int* __restrict__ cur)
{
    __shared__ int wsum[16];
    int b = blockIdx.x, tid = threadIdx.x;
    int lane = tid & 63, wv = tid >> 6;
    const int CHUNK = 20;
    int start = tid * CHUNK;
    int lc[CHUNK];
    int lsum = 0;
    #pragma unroll
    for (int i=0;i<CHUNK;i++){
        int n = start + i;
        int v = (n < N_) ? cnt[b*N_+n] : 0;
        lc[i] = v; lsum += v;
    }
    int v = lsum;
    #pragma unroll
    for (int off=1; off<64; off<<=1){
        int t = __shfl_up(v, off, 64);
        if (lane >= off) v += t;
    }
    if (lane == 63) wsum[wv] = v;
    __syncthreads();
    if (wv == 0 && lane < 16){
        int wv2 = wsum[lane];
        #pragma unroll
        for (int off=1; off<16; off<<=1){
            int t = __shfl_up(wv2, off, 64);
            if (lane >= off) wv2 += t;
        }
        wsum[lane] = wv2;
    }
    __syncthreads();
    int waveoff = (wv == 0) ? 0 : wsum[wv-1];
    int excl = waveoff + v - lsum;
    #pragma unroll
    for (int i=0;i<CHUNK;i++){
        int n = start + i;
        if (n < N_){
            rowptr[b*(N_+1)+n] = excl;
            cur[b*N_+n] = excl;
            excl += lc[i];
        }
    }
    if (tid == 0) rowptr[b*(N_+1)+N_] = E_;
}

__global__ __launch_bounds__(256) void fill_kernel(
    const int* __restrict__ edges, int* __restrict__ cur, int* __restrict__ csre)
{
    int idx = blockIdx.x*256 + threadIdx.x;
    if (idx >= B_*E_) return;
    int b = idx / E_, e = idx - b*E_;
    int t = edges[(size_t)idx*2];
    int pos = atomicAdd(cur + b*N_ + t, 1);
    csre[(size_t)b*E_ + pos] = e;
}

// ---------------- weight concat f32 -> bf16, all 3 layers once ----------------

__global__ __launch_bounds__(256) void wconv_kernel(
    const float* __restrict__ ww, const float* __restrict__ gw,
    unsigned short* __restrict__ wcat3)
{
    int o = blockIdx.x, l = blockIdx.y, t = threadIdx.x;
    const float* ww_l = ww + (size_t)l*C_*C_;
    const float* gw_l = gw + (size_t)l*C_*C_*3;
    int k = t*2;
    float a, bv;
    if (k < 128){ a = ww_l[(size_t)o*C_ + k];      bv = ww_l[(size_t)o*C_ + k + 1]; }
    else        { a = gw_l[(size_t)o*384 + k-128]; bv = gw_l[(size_t)o*384 + k-127]; }
    *(unsigned int*)&wcat3[((size_t)l*C_ + o)*512 + k] = pack2(a, bv);
}

__global__ __launch_bounds__(64) void fc1conv_kernel(
    const float* __restrict__ fc1w, unsigned short* __restrict__ w16)
{
    int o = blockIdx.x, t = threadIdx.x;
    int k = t*2;
    *(unsigned int*)&w16[(size_t)o*C_ + k] = pack2(fc1w[(size_t)o*C_+k], fc1w[(size_t)o*C_+k+1]);
}

// ---------------- per-layer: spectral reduce as MFMA GEMM ----------------

__global__ __launch_bounds__(256) void stageA_kernel(
    const unsigned short* __restrict__ hT, const unsigned short* __restrict__ wBt,
    float* __restrict__ part)
{
    __shared__ unsigned short As[80*72];   // [kcol][node], stride 72
    __shared__ unsigned short Bs[128*72];  // [c][node], stride 72
    int b = blockIdx.y, blk = blockIdx.x;
    int tid = threadIdx.x;
    int wv = tid>>6, lane = tid&63, l15 = lane&15, quad = lane>>4;
    floatx4 acc[5][2];
    #pragma unroll
    for (int mt=0;mt<5;mt++){ acc[mt][0]=(floatx4){0,0,0,0}; acc[mt][1]=(floatx4){0,0,0,0}; }
    size_t hbase = (size_t)b*C_*NPAD;
    size_t wbase = (size_t)b*80*NPAD;
    for (int cidx=0; cidx<5; ++cidx){
        int n0c = blk*320 + cidx*64;
        #pragma unroll
        for (int i=0;i<3;i++){
            int idx = i*256 + tid;
            if (idx < 640){
                int row = idx>>3, seg = idx&7;
                uintx4 v = __builtin_nontemporal_load(
                    (const uintx4*)&wBt[wbase + (size_t)row*NPAD + n0c + seg*8]);
                *(uintx4*)&As[row*72 + seg*8] = v;
            }
        }
        #pragma unroll
        for (int i=0;i<4;i++){
            int idx = i*256 + tid;
            int row = idx>>3, seg = idx&7;
            int node = n0c + seg*8;
            uintx4 v = (uintx4){0,0,0,0};
            if (node < N_)
                v = __builtin_nontemporal_load(
                    (const uintx4*)&hT[hbase + (size_t)row*NPAD + node]);
            *(uintx4*)&Bs[row*72 + seg*8] = v;
        }
        __syncthreads();
        #pragma unroll
        for (int ks=0; ks<2; ks++){
            short8 bfrag[2];
            #pragma unroll
            for (int ot=0;ot<2;ot++)
                bfrag[ot] = *(const short8*)&Bs[(wv*32+ot*16+l15)*72 + ks*32 + quad*8];
            #pragma unroll
            for (int mt=0;mt<5;mt++){
                short8 af = *(const short8*)&As[(mt*16+l15)*72 + ks*32 + quad*8];
                acc[mt][0] = __builtin_amdgcn_mfma_f32_16x16x32_bf16(af, bfrag[0], acc[mt][0], 0,0,0);
                acc[mt][1] = __builtin_amdgcn_mfma_f32_16x16x32_bf16(af, bfrag[1], acc[mt][1], 0,0,0);
            }
        }
        __syncthreads();
    }
    float* pblk = part + ((size_t)(b*64+blk))*80*C_;
    #pragma unroll
    for (int mt=0;mt<5;mt++){
        #pragma unroll
        for (int ot=0;ot<2;ot++){
            int c = wv*32 + ot*16 + l15;
            #pragma unroll
            for (int r=0;r<4;r++){
                int kcol = mt*16 + quad*4 + r;
                pblk[kcol*C_ + c] = acc[mt][ot][r];
            }
        }
    }
}

__global__ __launch_bounds__(256) void reducePart_kernel(
    const float* __restrict__ part, float* __restrict__ xq)
{
    int idx = blockIdx.x*256 + threadIdx.x;
    if (idx >= B_*80*C_) return;
    int b = idx / (80*C_);
    int r = idx - b*80*C_;
    float s = 0.f;
    for (int blk=0; blk<64; blk++)
        s += part[((size_t)(b*64+blk))*80*C_ + r];
    xq[idx] = s;
}

// ---------------- per-layer: mode mixing (one block per o, 4 b-groups) ----------------

__global__ __launch_bounds__(256) void mix_kernel(
    const float* __restrict__ xq, const float* __restrict__ swc_l,
    const float* __restrict__ sws_l, const float* __restrict__ sw0_l,
    unsigned short* __restrict__ wfb, float* __restrict__ f0)
{
    __shared__ float s64[4][64];
    int o = blockIdx.x, tid = threadIdx.x;
    int b = tid >> 6, t = tid & 63;
    int k = t & 31; bool isS = t >= 32;
    const float* xqb = xq + (size_t)b*80*C_;
    float acc = 0.f;
    for (int c=0;c<C_;c++){
        float xc = xqb[k*C_ + c], xs = xqb[(32+k)*C_ + c];
        float wc = swc_l[((size_t)c*C_+o)*K_ + k];
        float ws = sws_l[((size_t)c*C_+o)*K_ + k];
        acc += isS ? (xs*wc + xc*ws) : (xc*wc - xs*ws);
    }
    wfb[((size_t)b*C_+o)*64 + t] = f2bf(isS ? -2.f*acc : 2.f*acc);
    float p = xqb[64*C_ + t]      * sw0_l[(size_t)t*C_+o]
            + xqb[64*C_ + 64 + t] * sw0_l[(size_t)(t+64)*C_+o];
    s64[b][t] = p; __syncthreads();
    if (t==0){
        float s=0.f;
        for (int i=0;i<64;i++) s += s64[b][i];
        f0[b*C_+o] = s;
    }
}

// ---------------- per-layer: gradient gather (CSR), XCD-swizzled ----------------
// NT loads for one-shot edge streams; NT stores for g (consumer is on other XCDs).

__global__ __launch_bounds__(256) void grad_kernel(
    const unsigned short* __restrict__ hN, const int* __restrict__ edges,
    const float* __restrict__ egw, const int* __restrict__ rowptr,
    const int* __restrict__ csre, unsigned short* __restrict__ g)
{
    int flat = blockIdx.x;              // 20000 blocks
    int xcd = flat & 7;
    int b = xcd >> 1;
    int grp = (flat >> 3)*2 + (xcd & 1);    // 0..4999 within batch
    int n = grp*4 + (threadIdx.x >> 6);
    int cp = threadIdx.x & 63;
    size_t bN = (size_t)b*N_;
    size_t bE = (size_t)b*E_;
    int r0 = rowptr[b*(N_+1)+n], r1 = rowptr[b*(N_+1)+n+1];
    unsigned int hcu = *(const unsigned int*)&hN[(bN+n)*C_ + cp*2];
    float hc0 = bf2f((unsigned short)hcu), hc1 = bf2f((unsigned short)(hcu>>16));
    float a00=0.f,a01=0.f,a02=0.f, a10=0.f,a11=0.f,a12=0.f;
    int i = r0;
    for (; i + 1 < r1; i += 2){
        int e0 = __builtin_nontemporal_load(&csre[bE + i]);
        int e1 = __builtin_nontemporal_load(&csre[bE + i + 1]);
        size_t eb0 = bE + e0, eb1 = bE + e1;
        int s0 = __builtin_nontemporal_load(&edges[eb0*2+1]);
        int s1 = __builtin_nontemporal_load(&edges[eb1*2+1]);
        float w00 = __builtin_nontemporal_load(&egw[eb0*3+0]);
        float w01 = __builtin_nontemporal_load(&egw[eb0*3+1]);
        float w02 = __builtin_nontemporal_load(&egw[eb0*3+2]);
        float w10 = __builtin_nontemporal_load(&egw[eb1*3+0]);
        float w11 = __builtin_nontemporal_load(&egw[eb1*3+1]);
        float w12 = __builtin_nontemporal_load(&egw[eb1*3+2]);
        unsigned int u0 = *(const unsigned int*)&hN[(bN+s0)*C_ + cp*2];
        unsigned int u1 = *(const unsigned int*)&hN[(bN+s1)*C_ + cp*2];
        float d00 = bf2f((unsigned short)u0) - hc0;
        float d01 = bf2f((unsigned short)(u0>>16)) - hc1;
        float d10 = bf2f((unsigned short)u1) - hc0;
        float d11 = bf2f((unsigned short)(u1>>16)) - hc1;
        a00 += w00*d00; a01 += w01*d00; a02 += w02*d00;
        a10 += w00*d01; a11 += w01*d01; a12 += w02*d01;
        a00 += w10*d10; a01 += w11*d10; a02 += w12*d10;
        a10 += w10*d11; a11 += w11*d11; a12 += w12*d11;
    }
    if (i < r1){
        int e0 = __builtin_nontemporal_load(&csre[bE + i]);
        size_t eb0 = bE + e0;
        int s0 = __builtin_nontemporal_load(&edges[eb0*2+1]);
        float w00 = __builtin_nontemporal_load(&egw[eb0*3+0]);
        float w01 = __builtin_nontemporal_load(&egw[eb0*3+1]);
        float w02 = __builtin_nontemporal_load(&egw[eb0*3+2]);
        unsigned int u0 = *(const unsigned int*)&hN[(bN+s0)*C_ + cp*2];
        float d00 = bf2f((unsigned short)u0) - hc0;
        float d01 = bf2f((unsigned short)(u0>>16)) - hc1;
        a00 += w00*d00; a01 += w01*d00; a02 += w02*d00;
        a10 += w00*d01; a11 += w01*d01; a12 += w02*d01;
    }
    unsigned short* gr = g + (bN+n)*(size_t)384 + cp*6;
    __builtin_nontemporal_store(pack2(a00,a01), (unsigned int*)(gr+0));
    __builtin_nontemporal_store(pack2(a02,a10), (unsigned int*)(gr+2));
    __builtin_nontemporal_store(pack2(a11,a12), (unsigned int*)(gr+4));
}

// ---------------- per-layer: fused MFMA GEMM (K=576), R6 structure ----------------

__global__ __launch_bounds__(256) void gemm_kernel(
    const unsigned short* __restrict__ hN, const unsigned short* __restrict__ g,
    const unsigned short* __restrict__ bcb, const unsigned short* __restrict__ bsb,
    const unsigned short* __restrict__ wcat, const unsigned short* __restrict__ wfb,
    const float* __restrict__ wb_l, const float* __restrict__ gb_l,
    const float* __restrict__ f0,
    unsigned short* __restrict__ hNo, unsigned short* __restrict__ hT, int apply_gelu)
{
    __shared__ unsigned short As[2][64*72];
    int b = blockIdx.y;
    int nb0 = blockIdx.x*64;
    int tid = threadIdx.x;
    int a_n = tid>>2, a_s = tid&3;
    int wv = tid>>6, lane = tid&63, l15 = lane&15, quad = lane>>4;
    floatx4 acc[4][2];
    #pragma unroll
    for (int mt=0;mt<4;mt++)
        #pragma unroll
        for (int ot=0;ot<2;ot++) acc[mt][ot] = (floatx4){0.f,0.f,0.f,0.f};
    size_t bN = (size_t)b*N_;
    int gn = nb0 + a_n; bool av = gn < N_;
    size_t row = bN + (size_t)(av ? gn : 0);
    const unsigned short* hrow  = hN + row*C_;
    const unsigned short* grow  = g  + row*384;
    const unsigned short* bcrow = bcb + row*K_;
    const unsigned short* bsrow = bsb + row*K_;
    int o0 = wv*32 + l15, o1 = o0 + 16;
    const unsigned short* w0p = wcat + (size_t)o0*512 + quad*8;
    const unsigned short* w1p = wcat + (size_t)o1*512 + quad*8;
    const unsigned short* fb0 = wfb + ((size_t)b*C_ + o0)*64 + quad*8;
    const unsigned short* fb1 = wfb + ((size_t)b*C_ + o1)*64 + quad*8;

    auto loadA = [&](int ch, uintx4& v0, uintx4& v1){
        v0 = (uintx4){0,0,0,0}; v1 = (uintx4){0,0,0,0};
        if (av){
            if (ch < 8){
                const uintx4* p = (ch<2) ? (const uintx4*)(hrow + ch*64 + a_s*16)
                                         : (const uintx4*)(grow + (ch-2)*64 + a_s*16);
                v0 = __builtin_nontemporal_load(p);
                v1 = __builtin_nontemporal_load(p+1);
            } else {
                const uintx4* p = (a_s < 2) ? (const uintx4*)(bcrow + a_s*16)
                                            : (const uintx4*)(bsrow + (a_s-2)*16);
                v0 = __builtin_nontemporal_load(p);
                v1 = __builtin_nontemporal_load(p+1);
            }
        }
    };

    uintx4 c0, c1;
    loadA(0, c0, c1);
    *(uintx4*)&As[0][a_n*72 + a_s*16]     = c0;
    *(uintx4*)&As[0][a_n*72 + a_s*16 + 8] = c1;
    int p = 0;
    for (int ch=0; ch<9; ++ch){
        uintx4 n0v, n1v;
        if (ch < 8) loadA(ch+1, n0v, n1v);
        __syncthreads();
        #pragma unroll
        for (int ks=0; ks<2; ks++){
            short8 bfr0, bfr1;
            if (ch < 8){
                bfr0 = *(const short8*)(w0p + ch*64 + ks*32);
                bfr1 = *(const short8*)(w1p + ch*64 + ks*32);
            } else {
                bfr0 = *(const short8*)(fb0 + ks*32);
                bfr1 = *(const short8*)(fb1 + ks*32);
            }
            #pragma unroll
            for (int mt=0; mt<4; mt++){
                short8 af = *(const short8*)&As[p][(mt*16+l15)*72 + ks*32 + quad*8];
                acc[mt][0] = __builtin_amdgcn_mfma_f32_16x16x32_bf16(af, bfr0, acc[mt][0], 0,0,0);
                acc[mt][1] = __builtin_amdgcn_mfma_f32_16x16x32_bf16(af, bfr1, acc[mt][1], 0,0,0);
            }
        }
        if (ch < 8){
            *(uintx4*)&As[1-p][a_n*72 + a_s*16]     = n0v;
            *(uintx4*)&As[1-p][a_n*72 + a_s*16 + 8] = n1v;
            p ^= 1;
        }
    }
    float biasv[2]; int oo[2];
    oo[0]=o0; oo[1]=o1;
    #pragma unroll
    for (int ot=0;ot<2;ot++)
        biasv[ot] = wb_l[oo[ot]] + gb_l[oo[ot]] + f0[(size_t)b*C_ + oo[ot]];
    unsigned short* AsF = &As[0][0];   // reuse as [o][n] 128x72
    if (apply_gelu) __syncthreads();
    #pragma unroll
    for (int mt=0;mt<4;mt++){
        #pragma unroll
        for (int ot=0;ot<2;ot++){
            int nb = nb0 + mt*16 + quad*4;
            float v4[4];
            #pragma unroll
            for (int r=0;r<4;r++){
                float vv = acc[mt][ot][r] + biasv[ot];
                if (apply_gelu) vv = gelu_exact(vv);
                v4[r] = vv;
                if (nb + r < N_)
                    __builtin_nontemporal_store(f2bf(vv), &hNo[(bN+nb+r)*C_ + oo[ot]]);
            }
            if (apply_gelu){
                uintx2 u; u.x = pack2(v4[0],v4[1]); u.y = pack2(v4[2],v4[3]);
                *(uintx2*)&AsF[oo[ot]*72 + mt*16 + quad*4] = u;
            }
        }
    }
    if (apply_gelu){
        __syncthreads();
        int orow = tid>>1, half = tid&1;
        uintx4 u0 = *(const uintx4*)&AsF[orow*72 + half*32];
        uintx4 u1 = *(const uintx4*)&AsF[orow*72 + half*32 + 8];
        unsigned short* dst = &hT[((size_t)b*C_ + orow)*NPAD + nb0 + half*32];
        __builtin_nontemporal_store(u0, (uintx4*)dst);
        __builtin_nontemporal_store(u1, (uintx4*)(dst + 8));
    }
}

// ---------------- head: MFMA fc1 + gelu + fc2 ----------------

__global__ __launch_bounds__(256) void final_kernel(
    const unsigned short* __restrict__ hN, const unsigned short* __restrict__ fc1b16,
    const float* __restrict__ fc1b, const float* __restrict__ fc2w,
    const float* __restrict__ fc2b, float* __restrict__ out)
{
    __shared__ unsigned short As[64*72];
    __shared__ float pp[4*64];
    int b = blockIdx.y;
    int nb0 = blockIdx.x*64;
    int tid = threadIdx.x;
    int a_n = tid>>2, a_s = tid&3;
    int wv = tid>>6, lane = tid&63, l15 = lane&15, quad = lane>>4;
    floatx4 acc[4][2];
    #pragma unroll
    for (int mt=0;mt<4;mt++){ acc[mt][0]=(floatx4){0,0,0,0}; acc[mt][1]=(floatx4){0,0,0,0}; }
    size_t bN = (size_t)b*N_;
    int gn = nb0 + a_n; bool av = gn < N_;
    size_t row = bN + (size_t)(av ? gn : 0);
    const unsigned short* hrow = hN + row*C_;
    int o0 = wv*32 + l15, o1 = o0 + 16;
    const unsigned short* w0p = fc1b16 + (size_t)o0*C_ + quad*8;
    const unsigned short* w1p = fc1b16 + (size_t)o1*C_ + quad*8;

    for (int ch=0; ch<2; ++ch){
        uintx4 v0 = (uintx4){0,0,0,0}, v1 = (uintx4){0,0,0,0};
        if (av){
            const uintx4* pptr = (const uintx4*)(hrow + ch*64 + a_s*16);
            v0 = __builtin_nontemporal_load(pptr);
            v1 = __builtin_nontemporal_load(pptr+1);
        }
        *(uintx4*)&As[a_n*72 + a_s*16]     = v0;
        *(uintx4*)&As[a_n*72 + a_s*16 + 8] = v1;
        __syncthreads();
        #pragma unroll
        for (int ks=0; ks<2; ks++){
            short8 bfr0 = *(const short8*)(w0p + ch*64 + ks*32);
            short8 bfr1 = *(const short8*)(w1p + ch*64 + ks*32);
            #pragma unroll
            for (int mt=0; mt<4; mt++){
                short8 af = *(const short8*)&As[(mt*16+l15)*72 + ks*32 + quad*8];
                acc[mt][0] = __builtin_amdgcn_mfma_f32_16x16x32_bf16(af, bfr0, acc[mt][0], 0,0,0);
                acc[mt][1] = __builtin_amdgcn_mfma_f32_16x16x32_bf16(af, bfr1, acc[mt][1], 0,0,0);
            }
        }
        __syncthreads();
    }
    float fw0 = fc2w[o0], fw1 = fc2w[o1];
    float b0 = fc1b[o0], b1 = fc1b[o1];
    #pragma unroll
    for (int mt=0;mt<4;mt++){
        float s[4];
        #pragma unroll
        for (int r=0;r<4;r++)
            s[r] = fw0*gelu_exact(acc[mt][0][r] + b0) + fw1*gelu_exact(acc[mt][1][r] + b1);
        #pragma unroll
        for (int m=1;m<16;m<<=1)
            #pragma unroll
            for (int r=0;r<4;r++)
                s[r] += __shfl_xor(s[r], m, 16);
        if (l15 < 4){
            float v = (l15==0)?s[0]:(l15==1)?s[1]:(l15==2)?s[2]:s[3];
            pp[wv*64 + mt*16 + quad*4 + l15] = v;
        }
    }
    __syncthreads();
    if (tid < 64){
        float sum = pp[tid] + pp[64+tid] + pp[128+tid] + pp[192+tid] + fc2b[0];
        int n = nb0 + tid;
        if (n < N_) out[bN + n] = sum;
    }
}

// ---------------- launch ----------------

extern "C" void kernel_launch(void* const* d_in, const int* in_sizes, int n_in,
                              void* d_out, int out_size, void* d_ws, size_t ws_size,
                              hipStream_t stream)
{
    const float* x      = (const float*)d_in[0];
    const float* nodes  = (const float*)d_in[2];
    const float* nw     = (const float*)d_in[3];
    const int*   edges  = (const int*)  d_in[4];
    const float* egw    = (const float*)d_in[5];
    const float* modes  = (const float*)d_in[6];
    const float* latent = (const float*)d_in[7];
    const float* fc0w   = (const float*)d_in[8];
    const float* fc0b   = (const float*)d_in[9];
    const float* swc    = (const float*)d_in[10];
    const float* sws    = (const float*)d_in[11];
    const float* sw0    = (const float*)d_in[12];
    const float* ww     = (const float*)d_in[13];
    const float* wb     = (const float*)d_in[14];
    const float* gw     = (const float*)d_in[15];
    const float* gb     = (const float*)d_in[16];
    const float* fc1w   = (const float*)d_in[17];
    const float* fc1b   = (const float*)d_in[18];
    const float* fc2w   = (const float*)d_in[19];
    const float* fc2b   = (const float*)d_in[20];
    float* out = (float*)d_out;

    char* W = (char*)d_ws;
    size_t off = 0;
    unsigned short* bcB = (unsigned short*)(W+off); off += (size_t)NROWS*K_*2;
    unsigned short* bsB = (unsigned short*)(W+off); off += (size_t)NROWS*K_*2;
    unsigned short* wBt = (unsigned short*)(W+off); off += (size_t)B_*80*NPAD*2;
    unsigned short* hT  = (unsigned short*)(W+off); off += (size_t)B_*C_*NPAD*2;
    unsigned short* hNa = (unsigned short*)(W+off); off += (size_t)NROWS*C_*2;
    unsigned short* hNb = (unsigned short*)(W+off); off += (size_t)NROWS*C_*2;
    unsigned short* g   = (unsigned short*)(W+off); off += (size_t)NROWS*C_*3*2;
    unsigned short* wcat3=(unsigned short*)(W+off); off += (size_t)3*C_*512*2;
    unsigned short* wfb = (unsigned short*)(W+off); off += (size_t)B_*C_*64*2;
    unsigned short* fcw16=(unsigned short*)(W+off); off += (size_t)C_*C_*2;
    float* part = (float*)(W+off); off += (size_t)B_*64*80*C_*4;
    float* xq   = (float*)(W+off); off += (size_t)B_*80*C_*4;
    float* f0   = (float*)(W+off); off += (size_t)B_*C_*4;
    int* cnt    = (int*)(W+off); off += (size_t)B_*N_*4;
    int* rowptr = (int*)(W+off); off += (size_t)B_*(N_+1)*4 + 16;
    int* cur    = (int*)(W+off); off += (size_t)B_*N_*4;
    int* csre   = (int*)(W+off);

    (void)hipMemsetAsync(cnt, 0, (size_t)B_*N_*sizeof(int), stream);
    basis_kernel<<<dim3(NPAD/64, B_), 256, 0, stream>>>(
        nodes, nw, modes, latent, bcB, bsB, wBt);
    fc0_kernel  <<<(B_*N_+255)/256, 256, 0, stream>>>(x, fc0w, fc0b, hNa, hT);
    hist_kernel <<<(B_*E_+255)/256, 256, 0, stream>>>(edges, cnt);
    scan_kernel <<<B_, 1024, 0, stream>>>(cnt, rowptr, cur);
    fill_kernel <<<(B_*E_+255)/256, 256, 0, stream>>>(edges, cur, csre);
    wconv_kernel<<<dim3(C_,3), 256, 0, stream>>>(ww, gw, wcat3);
    fc1conv_kernel<<<C_, 64, 0, stream>>>(fc1w, fcw16);

    unsigned short* hc = hNa; unsigned short* hn = hNb;
    for (int l=0; l<3; ++l){
        stageA_kernel<<<dim3(64,B_), 256, 0, stream>>>(hT, wBt, part);
        reducePart_kernel<<<(B_*80*C_+255)/256, 256, 0, stream>>>(part, xq);
        mix_kernel<<<C_, 256, 0, stream>>>(
            xq, swc + (size_t)l*C_*C_*K_, sws + (size_t)l*C_*C_*K_,
            sw0 + (size_t)l*C_*C_, wfb, f0);
        grad_kernel<<<N_, 256, 0, stream>>>(hc, edges, egw, rowptr, csre, g);
        gemm_kernel<<<dim3((N_+63)/64,B_), 256, 0, stream>>>(
            hc, g, bcB, bsB, wcat3 + (size_t)l*C_*512, wfb,
            wb + (size_t)l*C_, gb + (size_t)l*C_,
            f0, hn, hT, (l<2) ? 1 : 0);
        unsigned short* t = hc; hc = hn; hn = t;
    }
    final_kernel<<<dim3((N_+63)/64,B_), 256, 0, stream>>>(
        hc, fcw16, fc1b, fc2w, fc2b, out);
}

// Round 12
// 615.760 us; speedup vs baseline: 1.2498x; 1.2498x over previous
//
#include <hip/hip_runtime.h>
#include <math.h>

#define B_ 4
#define N_ 20000
#define E_ 100000
#define C_ 128
#define K_ 32
#define NPAD 20480   // padded node count (multiple of 64)
#define NROWS (B_*N_ + 128)   // row slack so unguarded tile reads stay in-bounds

typedef __attribute__((ext_vector_type(8))) short short8;
typedef __attribute__((ext_vector_type(4))) float floatx4;
typedef __attribute__((ext_vector_type(4))) unsigned int uintx4;
typedef __attribute__((ext_vector_type(2))) unsigned int uintx2;

__device__ __forceinline__ float gelu_exact(float x){
    return 0.5f * x * (1.0f + erff(x * 0.70710678118654752f));
}

__device__ __forceinline__ unsigned short f2bf(float f){
    unsigned int u = __builtin_bit_cast(unsigned int, f);
    u += 0x7FFFu + ((u >> 16) & 1u);   // RNE
    return (unsigned short)(u >> 16);
}
__device__ __forceinline__ unsigned int pack2(float a, float b){
    return (unsigned int)f2bf(a) | ((unsigned int)f2bf(b) << 16);
}
__device__ __forceinline__ float bf2f(unsigned short u){
    unsigned int v = ((unsigned int)u) << 16;
    return __builtin_bit_cast(float, v);
}

// ---------------- setup: basis ----------------

__global__ __launch_bounds__(256) void basis_kernel(
    const float* __restrict__ nodes, const float* __restrict__ nw,
    const float* __restrict__ modes, const float* __restrict__ latent,
    unsigned short* __restrict__ bcb, unsigned short* __restrict__ bsb,
    unsigned short* __restrict__ wBt)
{
    __shared__ float lx[64], ly[64], lz[64], lwv[64];
    __shared__ unsigned short lTc[32*64], lTs[32*64];
    int b = blockIdx.y, n0 = blockIdx.x*64;
    int tid = threadIdx.x;
    size_t bN = (size_t)b*N_;
    if (tid < 64){
        int n = n0 + tid;
        float iL0 = 0.5f + 1.5f/(1.f+expf(-latent[0]));
        float iL1 = 0.5f + 1.5f/(1.f+expf(-latent[1]));
        float iL2 = 0.5f + 1.5f/(1.f+expf(-latent[2]));
        if (n < N_){
            lx[tid] = nodes[(bN+n)*3+0]*iL0;
            ly[tid] = nodes[(bN+n)*3+1]*iL1;
            lz[tid] = nodes[(bN+n)*3+2]*iL2;
            lwv[tid] = nw[bN+n];
        } else { lx[tid]=0.f; ly[tid]=0.f; lz[tid]=0.f; lwv[tid]=0.f; }
    }
    __syncthreads();
    int node = tid>>2, k0 = (tid&3)*8;
    float p0 = lx[node], p1 = ly[node], p2 = lz[node], w = lwv[node];
    float cv[8], sv[8];
    #pragma unroll
    for (int i=0;i<8;i++){
        int k = k0+i;
        float t = p0*modes[k*3+0] + p1*modes[k*3+1] + p2*modes[k*3+2];
        cv[i] = cosf(t); sv[i] = sinf(t);
        lTc[k*64 + node] = f2bf(w*cv[i]);
        lTs[k*64 + node] = f2bf(w*sv[i]);
    }
    int gn = n0 + node;
    if (gn < N_){
        uintx4 uc = (uintx4){pack2(cv[0],cv[1]), pack2(cv[2],cv[3]),
                             pack2(cv[4],cv[5]), pack2(cv[6],cv[7])};
        uintx4 us = (uintx4){pack2(sv[0],sv[1]), pack2(sv[2],sv[3]),
                             pack2(sv[4],sv[5]), pack2(sv[6],sv[7])};
        *(uintx4*)&bcb[(bN+gn)*K_ + k0] = uc;
        *(uintx4*)&bsb[(bN+gn)*K_ + k0] = us;
    }
    __syncthreads();
    #pragma unroll
    for (int i=0;i<5;i++){
        int idx = i*256 + tid;   // < 1280
        int row = idx>>4, seg = idx&15;
        unsigned short v0,v1,v2,v3;
        if (row < 32){
            v0=lTc[row*64+seg*4+0]; v1=lTc[row*64+seg*4+1];
            v2=lTc[row*64+seg*4+2]; v3=lTc[row*64+seg*4+3];
        } else if (row < 64){
            int r = row-32;
            v0=lTs[r*64+seg*4+0]; v1=lTs[r*64+seg*4+1];
            v2=lTs[r*64+seg*4+2]; v3=lTs[r*64+seg*4+3];
        } else if (row == 64){
            v0=f2bf(lwv[seg*4+0]); v1=f2bf(lwv[seg*4+1]);
            v2=f2bf(lwv[seg*4+2]); v3=f2bf(lwv[seg*4+3]);
        } else { v0=v1=v2=v3=0; }
        uintx2 u;
        u.x = (unsigned int)v0 | ((unsigned int)v1<<16);
        u.y = (unsigned int)v2 | ((unsigned int)v3<<16);
        *(uintx2*)&wBt[((size_t)b*80+row)*NPAD + n0 + seg*4] = u;
    }
}

// ---------------- setup: fc0 ----------------

__global__ __launch_bounds__(256) void fc0_kernel(
    const float* __restrict__ x, const float* __restrict__ w,
    const float* __restrict__ bvec, unsigned short* __restrict__ hN,
    unsigned short* __restrict__ hT)
{
    int idx = blockIdx.x*256 + threadIdx.x;
    if (idx >= B_*N_) return;
    int b = idx / N_, n = idx - b*N_;
    float x0 = x[(size_t)idx*3+0], x1 = x[(size_t)idx*3+1], x2 = x[(size_t)idx*3+2];
    unsigned short* hr = hN + (size_t)idx*C_;
    for (int c=0;c<C_;c+=4){
        float4 v;
        v.x = bvec[c+0] + x0*w[(c+0)*3] + x1*w[(c+0)*3+1] + x2*w[(c+0)*3+2];
        v.y = bvec[c+1] + x0*w[(c+1)*3] + x1*w[(c+1)*3+1] + x2*w[(c+1)*3+2];
        v.z = bvec[c+2] + x0*w[(c+2)*3] + x1*w[(c+2)*3+1] + x2*w[(c+2)*3+2];
        v.w = bvec[c+3] + x0*w[(c+3)*3] + x1*w[(c+3)*3+1] + x2*w[(c+3)*3+2];
        uintx2 u; u.x = pack2(v.x,v.y); u.y = pack2(v.z,v.w);
        *(uintx2*)(hr+c) = u;
        hT[((size_t)b*C_+c+0)*NPAD + n] = f2bf(v.x);
        hT[((size_t)b*C_+c+1)*NPAD + n] = f2bf(v.y);
        hT[((size_t)b*C_+c+2)*NPAD + n] = f2bf(v.z);
        hT[((size_t)b*C_+c+3)*NPAD + n] = f2bf(v.w);
    }
}

// ---------------- CSR build ----------------

__global__ __launch_bounds__(256) void hist_kernel(
    const int* __restrict__ edges, int* __restrict__ cnt)
{
    int idx = blockIdx.x*256 + threadIdx.x;
    if (idx >= B_*E_) return;
    int b = idx / E_;
    int t = edges[(size_t)idx*2];
    atomicAdd(cnt + b*N_ + t, 1);
}

__global__ __launch_bounds__(1024) void scan_kernel(
    const int* __restrict__ cnt, int* __restrict__ rowptr, int* __restrict__ cur)
{
    __shared__ int wsum[16];
    int b = blockIdx.x, tid = threadIdx.x;
    int lane = tid & 63, wv = tid >> 6;
    const int CHUNK = 20;
    int start = tid * CHUNK;
    int lc[CHUNK];
    int lsum = 0;
    #pragma unroll
    for (int i=0;i<CHUNK;i++){
        int n = start + i;
        int v = (n < N_) ? cnt[b*N_+n] : 0;
        lc[i] = v; lsum += v;
    }
    int v = lsum;
    #pragma unroll
    for (int off=1; off<64; off<<=1){
        int t = __shfl_up(v, off, 64);
        if (lane >= off) v += t;
    }
    if (lane == 63) wsum[wv] = v;
    __syncthreads();
    if (wv == 0 && lane < 16){
        int wv2 = wsum[lane];
        #pragma unroll
        for (int off=1; off<16; off<<=1){
            int t = __shfl_up(wv2, off, 64);
            if (lane >= off) wv2 += t;
        }
        wsum[lane] = wv2;
    }
    __syncthreads();
    int waveoff = (wv == 0) ? 0 : wsum[wv-1];
    int excl = waveoff + v - lsum;
    #pragma unroll
    for (int i=0;i<CHUNK;i++){
        int n = start + i;
        if (n < N_){
            rowptr[b*(N_+1)+n] = excl;
            cur[b*N_+n] = excl;
            excl += lc[i];
        }
    }
    if (tid == 0) rowptr[b*(N_+1)+N_] = E_;
}

__global__ __launch_bounds__(256) void fill_kernel(
    const int* __restrict__ edges, int* __restrict__ cur, int* __restrict__ csre)
{
    int idx = blockIdx.x*256 + threadIdx.x;
    if (idx >= B_*E_) return;
    int b = idx / E_, e = idx - b*E_;
    int t = edges[(size_t)idx*2];
    int pos = atomicAdd(cur + b*N_ + t, 1);
    csre[(size_t)b*E_ + pos] = e;
}

// ---------------- weight concat f32 -> bf16, all 3 layers once ----------------

__global__ __launch_bounds__(256) void wconv_kernel(
    const float* __restrict__ ww, const float* __restrict__ gw,
    unsigned short* __restrict__ wcat3)
{
    int o = blockIdx.x, l = blockIdx.y, t = threadIdx.x;
    const float* ww_l = ww + (size_t)l*C_*C_;
    const float* gw_l = gw + (size_t)l*C_*C_*3;
    int k = t*2;
    float a, bv;
    if (k < 128){ a = ww_l[(size_t)o*C_ + k];      bv = ww_l[(size_t)o*C_ + k + 1]; }
    else        { a = gw_l[(size_t)o*384 + k-128]; bv = gw_l[(size_t)o*384 + k-127]; }
    *(unsigned int*)&wcat3[((size_t)l*C_ + o)*512 + k] = pack2(a, bv);
}

__global__ __launch_bounds__(64) void fc1conv_kernel(
    const float* __restrict__ fc1w, unsigned short* __restrict__ w16)
{
    int o = blockIdx.x, t = threadIdx.x;
    int k = t*2;
    *(unsigned int*)&w16[(size_t)o*C_ + k] = pack2(fc1w[(size_t)o*C_+k], fc1w[(size_t)o*C_+k+1]);
}

// ---------------- per-layer: spectral reduce as MFMA GEMM ----------------

__global__ __launch_bounds__(256) void stageA_kernel(
    const unsigned short* __restrict__ hT, const unsigned short* __restrict__ wBt,
    float* __restrict__ part)
{
    __shared__ unsigned short As[80*72];   // [kcol][node], stride 72
    __shared__ unsigned short Bs[128*72];  // [c][node], stride 72
    int b = blockIdx.y, blk = blockIdx.x;
    int tid = threadIdx.x;
    int wv = tid>>6, lane = tid&63, l15 = lane&15, quad = lane>>4;
    floatx4 acc[5][2];
    #pragma unroll
    for (int mt=0;mt<5;mt++){ acc[mt][0]=(floatx4){0,0,0,0}; acc[mt][1]=(floatx4){0,0,0,0}; }
    size_t hbase = (size_t)b*C_*NPAD;
    size_t wbase = (size_t)b*80*NPAD;
    for (int cidx=0; cidx<5; ++cidx){
        int n0c = blk*320 + cidx*64;
        #pragma unroll
        for (int i=0;i<3;i++){
            int idx = i*256 + tid;
            if (idx < 640){
                int row = idx>>3, seg = idx&7;
                uintx4 v = *(const uintx4*)&wBt[wbase + (size_t)row*NPAD + n0c + seg*8];
                *(uintx4*)&As[row*72 + seg*8] = v;
            }
        }
        #pragma unroll
        for (int i=0;i<4;i++){
            int idx = i*256 + tid;
            int row = idx>>3, seg = idx&7;
            int node = n0c + seg*8;
            uintx4 v = (uintx4){0,0,0,0};
            if (node < N_)
                v = *(const uintx4*)&hT[hbase + (size_t)row*NPAD + node];
            *(uintx4*)&Bs[row*72 + seg*8] = v;
        }
        __syncthreads();
        #pragma unroll
        for (int ks=0; ks<2; ks++){
            short8 bfrag[2];
            #pragma unroll
            for (int ot=0;ot<2;ot++)
                bfrag[ot] = *(const short8*)&Bs[(wv*32+ot*16+l15)*72 + ks*32 + quad*8];
            #pragma unroll
            for (int mt=0;mt<5;mt++){
                short8 af = *(const short8*)&As[(mt*16+l15)*72 + ks*32 + quad*8];
                acc[mt][0] = __builtin_amdgcn_mfma_f32_16x16x32_bf16(af, bfrag[0], acc[mt][0], 0,0,0);
                acc[mt][1] = __builtin_amdgcn_mfma_f32_16x16x32_bf16(af, bfrag[1], acc[mt][1], 0,0,0);
            }
        }
        __syncthreads();
    }
    float* pblk = part + ((size_t)(b*64+blk))*80*C_;
    #pragma unroll
    for (int mt=0;mt<5;mt++){
        #pragma unroll
        for (int ot=0;ot<2;ot++){
            int c = wv*32 + ot*16 + l15;
            #pragma unroll
            for (int r=0;r<4;r++){
                int kcol = mt*16 + quad*4 + r;
                pblk[kcol*C_ + c] = acc[mt][ot][r];
            }
        }
    }
}

__global__ __launch_bounds__(256) void reducePart_kernel(
    const float* __restrict__ part, float* __restrict__ xq)
{
    int idx = blockIdx.x*256 + threadIdx.x;
    if (idx >= B_*80*C_) return;
    int b = idx / (80*C_);
    int r = idx - b*80*C_;
    float s = 0.f;
    for (int blk=0; blk<64; blk++)
        s += part[((size_t)(b*64+blk))*80*C_ + r];
    xq[idx] = s;
}

// ---------------- per-layer: mode mixing (one block per o, 4 b-groups) ----------------

__global__ __launch_bounds__(256) void mix_kernel(
    const float* __restrict__ xq, const float* __restrict__ swc_l,
    const float* __restrict__ sws_l, const float* __restrict__ sw0_l,
    unsigned short* __restrict__ wfb, float* __restrict__ f0)
{
    __shared__ float s64[4][64];
    int o = blockIdx.x, tid = threadIdx.x;
    int b = tid >> 6, t = tid & 63;
    int k = t & 31; bool isS = t >= 32;
    const float* xqb = xq + (size_t)b*80*C_;
    float acc = 0.f;
    for (int c=0;c<C_;c++){
        float xc = xqb[k*C_ + c], xs = xqb[(32+k)*C_ + c];
        float wc = swc_l[((size_t)c*C_+o)*K_ + k];
        float ws = sws_l[((size_t)c*C_+o)*K_ + k];
        acc += isS ? (xs*wc + xc*ws) : (xc*wc - xs*ws);
    }
    wfb[((size_t)b*C_+o)*64 + t] = f2bf(isS ? -2.f*acc : 2.f*acc);
    float p = xqb[64*C_ + t]      * sw0_l[(size_t)t*C_+o]
            + xqb[64*C_ + 64 + t] * sw0_l[(size_t)(t+64)*C_+o];
    s64[b][t] = p; __syncthreads();
    if (t==0){
        float s=0.f;
        for (int i=0;i<64;i++) s += s64[b][i];
        f0[b*C_+o] = s;
    }
}

// ---------------- per-layer: gradient gather (CSR), XCD-swizzled ----------------

__global__ __launch_bounds__(256) void grad_kernel(
    const unsigned short* __restrict__ hN, const int* __restrict__ edges,
    const float* __restrict__ egw, const int* __restrict__ rowptr,
    const int* __restrict__ csre, unsigned short* __restrict__ g)
{
    int flat = blockIdx.x;              // 20000 blocks
    int xcd = flat & 7;
    int b = xcd >> 1;
    int grp = (flat >> 3)*2 + (xcd & 1);    // 0..4999 within batch
    int n = grp*4 + (threadIdx.x >> 6);
    int cp = threadIdx.x & 63;
    size_t bN = (size_t)b*N_;
    size_t bE = (size_t)b*E_;
    int r0 = rowptr[b*(N_+1)+n], r1 = rowptr[b*(N_+1)+n+1];
    unsigned int hcu = *(const unsigned int*)&hN[(bN+n)*C_ + cp*2];
    float hc0 = bf2f((unsigned short)hcu), hc1 = bf2f((unsigned short)(hcu>>16));
    float a00=0.f,a01=0.f,a02=0.f, a10=0.f,a11=0.f,a12=0.f;
    int i = r0;
    for (; i + 1 < r1; i += 2){
        int e0 = csre[bE + i], e1 = csre[bE + i + 1];
        size_t eb0 = bE + e0, eb1 = bE + e1;
        int s0 = edges[eb0*2+1], s1 = edges[eb1*2+1];
        float w00 = egw[eb0*3+0], w01 = egw[eb0*3+1], w02 = egw[eb0*3+2];
        float w10 = egw[eb1*3+0], w11 = egw[eb1*3+1], w12 = egw[eb1*3+2];
        unsigned int u0 = *(const unsigned int*)&hN[(bN+s0)*C_ + cp*2];
        unsigned int u1 = *(const unsigned int*)&hN[(bN+s1)*C_ + cp*2];
        float d00 = bf2f((unsigned short)u0) - hc0;
        float d01 = bf2f((unsigned short)(u0>>16)) - hc1;
        float d10 = bf2f((unsigned short)u1) - hc0;
        float d11 = bf2f((unsigned short)(u1>>16)) - hc1;
        a00 += w00*d00; a01 += w01*d00; a02 += w02*d00;
        a10 += w00*d01; a11 += w01*d01; a12 += w02*d01;
        a00 += w10*d10; a01 += w11*d10; a02 += w12*d10;
        a10 += w10*d11; a11 += w11*d11; a12 += w12*d11;
    }
    if (i < r1){
        int e0 = csre[bE + i];
        size_t eb0 = bE + e0;
        int s0 = edges[eb0*2+1];
        float w00 = egw[eb0*3+0], w01 = egw[eb0*3+1], w02 = egw[eb0*3+2];
        unsigned int u0 = *(const unsigned int*)&hN[(bN+s0)*C_ + cp*2];
        float d00 = bf2f((unsigned short)u0) - hc0;
        float d01 = bf2f((unsigned short)(u0>>16)) - hc1;
        a00 += w00*d00; a01 += w01*d00; a02 += w02*d00;
        a10 += w00*d01; a11 += w01*d01; a12 += w02*d01;
    }
    unsigned short* gr = g + (bN+n)*(size_t)384 + cp*6;
    *(unsigned int*)(gr+0) = pack2(a00,a01);
    *(unsigned int*)(gr+2) = pack2(a02,a10);
    *(unsigned int*)(gr+4) = pack2(a11,a12);
}

// ---------------- per-layer: fused MFMA GEMM (K=576), R6 structure ----------------

__global__ __launch_bounds__(256) void gemm_kernel(
    const unsigned short* __restrict__ hN, const unsigned short* __restrict__ g,
    const unsigned short* __restrict__ bcb, const unsigned short* __restrict__ bsb,
    const unsigned short* __restrict__ wcat, const unsigned short* __restrict__ wfb,
    const float* __restrict__ wb_l, const float* __restrict__ gb_l,
    const float* __restrict__ f0,
    unsigned short* __restrict__ hNo, unsigned short* __restrict__ hT, int apply_gelu)
{
    __shared__ unsigned short As[2][64*72];
    int b = blockIdx.y;
    int nb0 = blockIdx.x*64;
    int tid = threadIdx.x;
    int a_n = tid>>2, a_s = tid&3;
    int wv = tid>>6, lane = tid&63, l15 = lane&15, quad = lane>>4;
    floatx4 acc[4][2];
    #pragma unroll
    for (int mt=0;mt<4;mt++)
        #pragma unroll
        for (int ot=0;ot<2;ot++) acc[mt][ot] = (floatx4){0.f,0.f,0.f,0.f};
    size_t bN = (size_t)b*N_;
    int gn = nb0 + a_n; bool av = gn < N_;
    size_t row = bN + (size_t)(av ? gn : 0);
    const unsigned short* hrow  = hN + row*C_;
    const unsigned short* grow  = g  + row*384;
    const unsigned short* bcrow = bcb + row*K_;
    const unsigned short* bsrow = bsb + row*K_;
    int o0 = wv*32 + l15, o1 = o0 + 16;
    const unsigned short* w0p = wcat + (size_t)o0*512 + quad*8;
    const unsigned short* w1p = wcat + (size_t)o1*512 + quad*8;
    const unsigned short* fb0 = wfb + ((size_t)b*C_ + o0)*64 + quad*8;
    const unsigned short* fb1 = wfb + ((size_t)b*C_ + o1)*64 + quad*8;

    auto loadA = [&](int ch, uintx4& v0, uintx4& v1){
        v0 = (uintx4){0,0,0,0}; v1 = (uintx4){0,0,0,0};
        if (av){
            if (ch < 8){
                const uintx4* p = (ch<2) ? (const uintx4*)(hrow + ch*64 + a_s*16)
                                         : (const uintx4*)(grow + (ch-2)*64 + a_s*16);
                v0 = p[0]; v1 = p[1];
            } else {
                const uintx4* p = (a_s < 2) ? (const uintx4*)(bcrow + a_s*16)
                                            : (const uintx4*)(bsrow + (a_s-2)*16);
                v0 = p[0]; v1 = p[1];
            }
        }
    };

    uintx4 c0, c1;
    loadA(0, c0, c1);
    *(uintx4*)&As[0][a_n*72 + a_s*16]     = c0;
    *(uintx4*)&As[0][a_n*72 + a_s*16 + 8] = c1;
    int p = 0;
    for (int ch=0; ch<9; ++ch){
        uintx4 n0v, n1v;
        if (ch < 8) loadA(ch+1, n0v, n1v);
        __syncthreads();
        #pragma unroll
        for (int ks=0; ks<2; ks++){
            short8 bfr0, bfr1;
            if (ch < 8){
                bfr0 = *(const short8*)(w0p + ch*64 + ks*32);
                bfr1 = *(const short8*)(w1p + ch*64 + ks*32);
            } else {
                bfr0 = *(const short8*)(fb0 + ks*32);
                bfr1 = *(const short8*)(fb1 + ks*32);
            }
            #pragma unroll
            for (int mt=0; mt<4; mt++){
                short8 af = *(const short8*)&As[p][(mt*16+l15)*72 + ks*32 + quad*8];
                acc[mt][0] = __builtin_amdgcn_mfma_f32_16x16x32_bf16(af, bfr0, acc[mt][0], 0,0,0);
                acc[mt][1] = __builtin_amdgcn_mfma_f32_16x16x32_bf16(af, bfr1, acc[mt][1], 0,0,0);
            }
        }
        if (ch < 8){
            *(uintx4*)&As[1-p][a_n*72 + a_s*16]     = n0v;
            *(uintx4*)&As[1-p][a_n*72 + a_s*16 + 8] = n1v;
            p ^= 1;
        }
    }
    float biasv[2]; int oo[2];
    oo[0]=o0; oo[1]=o1;
    #pragma unroll
    for (int ot=0;ot<2;ot++)
        biasv[ot] = wb_l[oo[ot]] + gb_l[oo[ot]] + f0[(size_t)b*C_ + oo[ot]];
    unsigned short* AsF = &As[0][0];   // reuse as [o][n] 128x72
    if (apply_gelu) __syncthreads();
    #pragma unroll
    for (int mt=0;mt<4;mt++){
        #pragma unroll
        for (int ot=0;ot<2;ot++){
            int nb = nb0 + mt*16 + quad*4;
            float v4[4];
            #pragma unroll
            for (int r=0;r<4;r++){
                float vv = acc[mt][ot][r] + biasv[ot];
                if (apply_gelu) vv = gelu_exact(vv);
                v4[r] = vv;
                if (nb + r < N_) hNo[(bN+nb+r)*C_ + oo[ot]] = f2bf(vv);
            }
            if (apply_gelu){
                uintx2 u; u.x = pack2(v4[0],v4[1]); u.y = pack2(v4[2],v4[3]);
                *(uintx2*)&AsF[oo[ot]*72 + mt*16 + quad*4] = u;
            }
        }
    }
    if (apply_gelu){
        __syncthreads();
        int orow = tid>>1, half = tid&1;
        uintx4 u0 = *(const uintx4*)&AsF[orow*72 + half*32];
        uintx4 u1 = *(const uintx4*)&AsF[orow*72 + half*32 + 8];
        unsigned short* dst = &hT[((size_t)b*C_ + orow)*NPAD + nb0 + half*32];
        *(uintx4*)dst       = u0;
        *(uintx4*)(dst + 8) = u1;
    }
}

// ---------------- head: MFMA fc1 + gelu + fc2 ----------------

__global__ __launch_bounds__(256) void final_kernel(
    const unsigned short* __restrict__ hN, const unsigned short* __restrict__ fc1b16,
    const float* __restrict__ fc1b, const float* __restrict__ fc2w,
    const float* __restrict__ fc2b, float* __restrict__ out)
{
    __shared__ unsigned short As[64*72];
    __shared__ float pp[4*64];
    int b = blockIdx.y;
    int nb0 = blockIdx.x*64;
    int tid = threadIdx.x;
    int a_n = tid>>2, a_s = tid&3;
    int wv = tid>>6, lane = tid&63, l15 = lane&15, quad = lane>>4;
    floatx4 acc[4][2];
    #pragma unroll
    for (int mt=0;mt<4;mt++){ acc[mt][0]=(floatx4){0,0,0,0}; acc[mt][1]=(floatx4){0,0,0,0}; }
    size_t bN = (size_t)b*N_;
    int gn = nb0 + a_n; bool av = gn < N_;
    size_t row = bN + (size_t)(av ? gn : 0);
    const unsigned short* hrow = hN + row*C_;
    int o0 = wv*32 + l15, o1 = o0 + 16;
    const unsigned short* w0p = fc1b16 + (size_t)o0*C_ + quad*8;
    const unsigned short* w1p = fc1b16 + (size_t)o1*C_ + quad*8;

    for (int ch=0; ch<2; ++ch){
        uintx4 v0 = (uintx4){0,0,0,0}, v1 = (uintx4){0,0,0,0};
        if (av){
            const uintx4* pptr = (const uintx4*)(hrow + ch*64 + a_s*16);
            v0 = pptr[0]; v1 = pptr[1];
        }
        *(uintx4*)&As[a_n*72 + a_s*16]     = v0;
        *(uintx4*)&As[a_n*72 + a_s*16 + 8] = v1;
        __syncthreads();
        #pragma unroll
        for (int ks=0; ks<2; ks++){
            short8 bfr0 = *(const short8*)(w0p + ch*64 + ks*32);
            short8 bfr1 = *(const short8*)(w1p + ch*64 + ks*32);
            #pragma unroll
            for (int mt=0; mt<4; mt++){
                short8 af = *(const short8*)&As[(mt*16+l15)*72 + ks*32 + quad*8];
                acc[mt][0] = __builtin_amdgcn_mfma_f32_16x16x32_bf16(af, bfr0, acc[mt][0], 0,0,0);
                acc[mt][1] = __builtin_amdgcn_mfma_f32_16x16x32_bf16(af, bfr1, acc[mt][1], 0,0,0);
            }
        }
        __syncthreads();
    }
    float fw0 = fc2w[o0], fw1 = fc2w[o1];
    float b0 = fc1b[o0], b1 = fc1b[o1];
    #pragma unroll
    for (int mt=0;mt<4;mt++){
        float s[4];
        #pragma unroll
        for (int r=0;r<4;r++)
            s[r] = fw0*gelu_exact(acc[mt][0][r] + b0) + fw1*gelu_exact(acc[mt][1][r] + b1);
        #pragma unroll
        for (int m=1;m<16;m<<=1)
            #pragma unroll
            for (int r=0;r<4;r++)
                s[r] += __shfl_xor(s[r], m, 16);
        if (l15 < 4){
            float v = (l15==0)?s[0]:(l15==1)?s[1]:(l15==2)?s[2]:s[3];
            pp[wv*64 + mt*16 + quad*4 + l15] = v;
        }
    }
    __syncthreads();
    if (tid < 64){
        float sum = pp[tid] + pp[64+tid] + pp[128+tid] + pp[192+tid] + fc2b[0];
        int n = nb0 + tid;
        if (n < N_) out[bN + n] = sum;
    }
}

// ---------------- launch ----------------

extern "C" void kernel_launch(void* const* d_in, const int* in_sizes, int n_in,
                              void* d_out, int out_size, void* d_ws, size_t ws_size,
                              hipStream_t stream)
{
    const float* x      = (const float*)d_in[0];
    const float* nodes  = (const float*)d_in[2];
    const float* nw     = (const float*)d_in[3];
    const int*   edges  = (const int*)  d_in[4];
    const float* egw    = (const float*)d_in[5];
    const float* modes  = (const float*)d_in[6];
    const float* latent = (const float*)d_in[7];
    const float* fc0w   = (const float*)d_in[8];
    const float* fc0b   = (const float*)d_in[9];
    const float* swc    = (const float*)d_in[10];
    const float* sws    = (const float*)d_in[11];
    const float* sw0    = (const float*)d_in[12];
    const float* ww     = (const float*)d_in[13];
    const float* wb     = (const float*)d_in[14];
    const float* gw     = (const float*)d_in[15];
    const float* gb     = (const float*)d_in[16];
    const float* fc1w   = (const float*)d_in[17];
    const float* fc1b   = (const float*)d_in[18];
    const float* fc2w   = (const float*)d_in[19];
    const float* fc2b   = (const float*)d_in[20];
    float* out = (float*)d_out;

    char* W = (char*)d_ws;
    size_t off = 0;
    unsigned short* bcB = (unsigned short*)(W+off); off += (size_t)NROWS*K_*2;
    unsigned short* bsB = (unsigned short*)(W+off); off += (size_t)NROWS*K_*2;
    unsigned short* wBt = (unsigned short*)(W+off); off += (size_t)B_*80*NPAD*2;
    unsigned short* hT  = (unsigned short*)(W+off); off += (size_t)B_*C_*NPAD*2;
    unsigned short* hNa = (unsigned short*)(W+off); off += (size_t)NROWS*C_*2;
    unsigned short* hNb = (unsigned short*)(W+off); off += (size_t)NROWS*C_*2;
    unsigned short* g   = (unsigned short*)(W+off); off += (size_t)NROWS*C_*3*2;
    unsigned short* wcat3=(unsigned short*)(W+off); off += (size_t)3*C_*512*2;
    unsigned short* wfb = (unsigned short*)(W+off); off += (size_t)B_*C_*64*2;
    unsigned short* fcw16=(unsigned short*)(W+off); off += (size_t)C_*C_*2;
    float* part = (float*)(W+off); off += (size_t)B_*64*80*C_*4;
    float* xq   = (float*)(W+off); off += (size_t)B_*80*C_*4;
    float* f0   = (float*)(W+off); off += (size_t)B_*C_*4;
    int* cnt    = (int*)(W+off); off += (size_t)B_*N_*4;
    int* rowptr = (int*)(W+off); off += (size_t)B_*(N_+1)*4 + 16;
    int* cur    = (int*)(W+off); off += (size_t)B_*N_*4;
    int* csre   = (int*)(W+off);

    (void)hipMemsetAsync(cnt, 0, (size_t)B_*N_*sizeof(int), stream);
    basis_kernel<<<dim3(NPAD/64, B_), 256, 0, stream>>>(
        nodes, nw, modes, latent, bcB, bsB, wBt);
    fc0_kernel  <<<(B_*N_+255)/256, 256, 0, stream>>>(x, fc0w, fc0b, hNa, hT);
    hist_kernel <<<(B_*E_+255)/256, 256, 0, stream>>>(edges, cnt);
    scan_kernel <<<B_, 1024, 0, stream>>>(cnt, rowptr, cur);
    fill_kernel <<<(B_*E_+255)/256, 256, 0, stream>>>(edges, cur, csre);
    wconv_kernel<<<dim3(C_,3), 256, 0, stream>>>(ww, gw, wcat3);
    fc1conv_kernel<<<C_, 64, 0, stream>>>(fc1w, fcw16);

    unsigned short* hc = hNa; unsigned short* hn = hNb;
    for (int l=0; l<3; ++l){
        stageA_kernel<<<dim3(64,B_), 256, 0, stream>>>(hT, wBt, part);
        reducePart_kernel<<<(B_*80*C_+255)/256, 256, 0, stream>>>(part, xq);
        mix_kernel<<<C_, 256, 0, stream>>>(
            xq, swc + (size_t)l*C_*C_*K_, sws + (size_t)l*C_*C_*K_,
            sw0 + (size_t)l*C_*C_, wfb, f0);
        grad_kernel<<<N_, 256, 0, stream>>>(hc, edges, egw, rowptr, csre, g);
        gemm_kernel<<<dim3((N_+63)/64,B_), 256, 0, stream>>>(
            hc, g, bcB, bsB, wcat3 + (size_t)l*C_*512, wfb,
            wb + (size_t)l*C_, gb + (size_t)l*C_,
            f0, hn, hT, (l<2) ? 1 : 0);
        unsigned short* t = hc; hc = hn; hn = t;
    }
    final_kernel<<<dim3((N_+63)/64,B_), 256, 0, stream>>>(
        hc, fcw16, fc1b, fc2w, fc2b, out);
}

// Round 13
// 576.407 us; speedup vs baseline: 1.3352x; 1.0683x over previous
//
#include <hip/hip_runtime.h>
#include <math.h>

#define B_ 4
#define N_ 20000
#define E_ 100000
#define C_ 128
#define K_ 32
#define NPAD 20480   // padded node count (multiple of 64)
#define NROWS (B_*N_ + 128)   // row slack so unguarded tile reads stay in-bounds

typedef __attribute__((ext_vector_type(8))) short short8;
typedef __attribute__((ext_vector_type(4))) float floatx4;
typedef __attribute__((ext_vector_type(4))) unsigned int uintx4;
typedef __attribute__((ext_vector_type(2))) unsigned int uintx2;

__device__ __forceinline__ float gelu_exact(float x){
    return 0.5f * x * (1.0f + erff(x * 0.70710678118654752f));
}

__device__ __forceinline__ unsigned short f2bf(float f){
    unsigned int u = __builtin_bit_cast(unsigned int, f);
    u += 0x7FFFu + ((u >> 16) & 1u);   // RNE
    return (unsigned short)(u >> 16);
}
__device__ __forceinline__ unsigned int pack2(float a, float b){
    return (unsigned int)f2bf(a) | ((unsigned int)f2bf(b) << 16);
}
__device__ __forceinline__ float bf2f(unsigned short u){
    unsigned int v = ((unsigned int)u) << 16;
    return __builtin_bit_cast(float, v);
}
__device__ __forceinline__ float u2f(unsigned int u){
    return __builtin_bit_cast(float, u);
}

// ---------------- setup: basis ----------------

__global__ __launch_bounds__(256) void basis_kernel(
    const float* __restrict__ nodes, const float* __restrict__ nw,
    const float* __restrict__ modes, const float* __restrict__ latent,
    unsigned short* __restrict__ bcb, unsigned short* __restrict__ bsb,
    unsigned short* __restrict__ wBt)
{
    __shared__ float lx[64], ly[64], lz[64], lwv[64];
    __shared__ unsigned short lTc[32*64], lTs[32*64];
    int b = blockIdx.y, n0 = blockIdx.x*64;
    int tid = threadIdx.x;
    size_t bN = (size_t)b*N_;
    if (tid < 64){
        int n = n0 + tid;
        float iL0 = 0.5f + 1.5f/(1.f+expf(-latent[0]));
        float iL1 = 0.5f + 1.5f/(1.f+expf(-latent[1]));
        float iL2 = 0.5f + 1.5f/(1.f+expf(-latent[2]));
        if (n < N_){
            lx[tid] = nodes[(bN+n)*3+0]*iL0;
            ly[tid] = nodes[(bN+n)*3+1]*iL1;
            lz[tid] = nodes[(bN+n)*3+2]*iL2;
            lwv[tid] = nw[bN+n];
        } else { lx[tid]=0.f; ly[tid]=0.f; lz[tid]=0.f; lwv[tid]=0.f; }
    }
    __syncthreads();
    int node = tid>>2, k0 = (tid&3)*8;
    float p0 = lx[node], p1 = ly[node], p2 = lz[node], w = lwv[node];
    float cv[8], sv[8];
    #pragma unroll
    for (int i=0;i<8;i++){
        int k = k0+i;
        float t = p0*modes[k*3+0] + p1*modes[k*3+1] + p2*modes[k*3+2];
        cv[i] = cosf(t); sv[i] = sinf(t);
        lTc[k*64 + node] = f2bf(w*cv[i]);
        lTs[k*64 + node] = f2bf(w*sv[i]);
    }
    int gn = n0 + node;
    if (gn < N_){
        uintx4 uc = (uintx4){pack2(cv[0],cv[1]), pack2(cv[2],cv[3]),
                             pack2(cv[4],cv[5]), pack2(cv[6],cv[7])};
        uintx4 us = (uintx4){pack2(sv[0],sv[1]), pack2(sv[2],sv[3]),
                             pack2(sv[4],sv[5]), pack2(sv[6],sv[7])};
        *(uintx4*)&bcb[(bN+gn)*K_ + k0] = uc;
        *(uintx4*)&bsb[(bN+gn)*K_ + k0] = us;
    }
    __syncthreads();
    #pragma unroll
    for (int i=0;i<5;i++){
        int idx = i*256 + tid;   // < 1280
        int row = idx>>4, seg = idx&15;
        unsigned short v0,v1,v2,v3;
        if (row < 32){
            v0=lTc[row*64+seg*4+0]; v1=lTc[row*64+seg*4+1];
            v2=lTc[row*64+seg*4+2]; v3=lTc[row*64+seg*4+3];
        } else if (row < 64){
            int r = row-32;
            v0=lTs[r*64+seg*4+0]; v1=lTs[r*64+seg*4+1];
            v2=lTs[r*64+seg*4+2]; v3=lTs[r*64+seg*4+3];
        } else if (row == 64){
            v0=f2bf(lwv[seg*4+0]); v1=f2bf(lwv[seg*4+1]);
            v2=f2bf(lwv[seg*4+2]); v3=f2bf(lwv[seg*4+3]);
        } else { v0=v1=v2=v3=0; }
        uintx2 u;
        u.x = (unsigned int)v0 | ((unsigned int)v1<<16);
        u.y = (unsigned int)v2 | ((unsigned int)v3<<16);
        *(uintx2*)&wBt[((size_t)b*80+row)*NPAD + n0 + seg*4] = u;
    }
}

// ---------------- setup: fc0 ----------------

__global__ __launch_bounds__(256) void fc0_kernel(
    const float* __restrict__ x, const float* __restrict__ w,
    const float* __restrict__ bvec, unsigned short* __restrict__ hN,
    unsigned short* __restrict__ hT)
{
    int idx = blockIdx.x*256 + threadIdx.x;
    if (idx >= B_*N_) return;
    int b = idx / N_, n = idx - b*N_;
    float x0 = x[(size_t)idx*3+0], x1 = x[(size_t)idx*3+1], x2 = x[(size_t)idx*3+2];
    unsigned short* hr = hN + (size_t)idx*C_;
    for (int c=0;c<C_;c+=4){
        float4 v;
        v.x = bvec[c+0] + x0*w[(c+0)*3] + x1*w[(c+0)*3+1] + x2*w[(c+0)*3+2];
        v.y = bvec[c+1] + x0*w[(c+1)*3] + x1*w[(c+1)*3+1] + x2*w[(c+1)*3+2];
        v.z = bvec[c+2] + x0*w[(c+2)*3] + x1*w[(c+2)*3+1] + x2*w[(c+2)*3+2];
        v.w = bvec[c+3] + x0*w[(c+3)*3] + x1*w[(c+3)*3+1] + x2*w[(c+3)*3+2];
        uintx2 u; u.x = pack2(v.x,v.y); u.y = pack2(v.z,v.w);
        *(uintx2*)(hr+c) = u;
        hT[((size_t)b*C_+c+0)*NPAD + n] = f2bf(v.x);
        hT[((size_t)b*C_+c+1)*NPAD + n] = f2bf(v.y);
        hT[((size_t)b*C_+c+2)*NPAD + n] = f2bf(v.z);
        hT[((size_t)b*C_+c+3)*NPAD + n] = f2bf(v.w);
    }
}

// ---------------- CSR build ----------------

__global__ __launch_bounds__(256) void hist_kernel(
    const int* __restrict__ edges, int* __restrict__ cnt)
{
    int idx = blockIdx.x*256 + threadIdx.x;
    if (idx >= B_*E_) return;
    int b = idx / E_;
    int t = edges[(size_t)idx*2];
    atomicAdd(cnt + b*N_ + t, 1);
}

__global__ __launch_bounds__(1024) void scan_kernel(
    const int* __restrict__ cnt, int* __restrict__ rowptr, int* __restrict__ cur)
{
    __shared__ int wsum[16];
    int b = blockIdx.x, tid = threadIdx.x;
    int lane = tid & 63, wv = tid >> 6;
    const int CHUNK = 20;
    int start = tid * CHUNK;
    int lc[CHUNK];
    int lsum = 0;
    #pragma unroll
    for (int i=0;i<CHUNK;i++){
        int n = start + i;
        int v = (n < N_) ? cnt[b*N_+n] : 0;
        lc[i] = v; lsum += v;
    }
    int v = lsum;
    #pragma unroll
    for (int off=1; off<64; off<<=1){
        int t = __shfl_up(v, off, 64);
        if (lane >= off) v += t;
    }
    if (lane == 63) wsum[wv] = v;
    __syncthreads();
    if (wv == 0 && lane < 16){
        int wv2 = wsum[lane];
        #pragma unroll
        for (int off=1; off<16; off<<=1){
            int t = __shfl_up(wv2, off, 64);
            if (lane >= off) wv2 += t;
        }
        wsum[lane] = wv2;
    }
    __syncthreads();
    int waveoff = (wv == 0) ? 0 : wsum[wv-1];
    int excl = waveoff + v - lsum;
    #pragma unroll
    for (int i=0;i<CHUNK;i++){
        int n = start + i;
        if (n < N_){
            rowptr[b*(N_+1)+n] = excl;
            cur[b*N_+n] = excl;
            excl += lc[i];
        }
    }
    if (tid == 0) rowptr[b*(N_+1)+N_] = E_;
}

// fill: build CSR-ordered packed edge records {src, w0, w1, w2} (16 B)
__global__ __launch_bounds__(256) void fill_kernel(
    const int* __restrict__ edges, const float* __restrict__ egw,
    int* __restrict__ cur, uintx4* __restrict__ epack)
{
    int idx = blockIdx.x*256 + threadIdx.x;
    if (idx >= B_*E_) return;
    int b = idx / E_;
    int t = edges[(size_t)idx*2];
    int src = edges[(size_t)idx*2+1];
    uintx4 rec;
    rec.x = (unsigned int)src;
    rec.y = __builtin_bit_cast(unsigned int, egw[(size_t)idx*3+0]);
    rec.z = __builtin_bit_cast(unsigned int, egw[(size_t)idx*3+1]);
    rec.w = __builtin_bit_cast(unsigned int, egw[(size_t)idx*3+2]);
    int pos = atomicAdd(cur + b*N_ + t, 1);
    epack[(size_t)b*E_ + pos] = rec;
}

// ---------------- weight concat f32 -> bf16, all 3 layers once ----------------

__global__ __launch_bounds__(256) void wconv_kernel(
    const float* __restrict__ ww, const float* __restrict__ gw,
    unsigned short* __restrict__ wcat3)
{
    int o = blockIdx.x, l = blockIdx.y, t = threadIdx.x;
    const float* ww_l = ww + (size_t)l*C_*C_;
    const float* gw_l = gw + (size_t)l*C_*C_*3;
    int k = t*2;
    float a, bv;
    if (k < 128){ a = ww_l[(size_t)o*C_ + k];      bv = ww_l[(size_t)o*C_ + k + 1]; }
    else        { a = gw_l[(size_t)o*384 + k-128]; bv = gw_l[(size_t)o*384 + k-127]; }
    *(unsigned int*)&wcat3[((size_t)l*C_ + o)*512 + k] = pack2(a, bv);
}

__global__ __launch_bounds__(64) void fc1conv_kernel(
    const float* __restrict__ fc1w, unsigned short* __restrict__ w16)
{
    int o = blockIdx.x, t = threadIdx.x;
    int k = t*2;
    *(unsigned int*)&w16[(size_t)o*C_ + k] = pack2(fc1w[(size_t)o*C_+k], fc1w[(size_t)o*C_+k+1]);
}

// ---------------- per-layer: spectral reduce as MFMA GEMM ----------------

__global__ __launch_bounds__(256) void stageA_kernel(
    const unsigned short* __restrict__ hT, const unsigned short* __restrict__ wBt,
    float* __restrict__ part)
{
    __shared__ unsigned short As[80*72];   // [kcol][node], stride 72
    __shared__ unsigned short Bs[128*72];  // [c][node], stride 72
    int b = blockIdx.y, blk = blockIdx.x;
    int tid = threadIdx.x;
    int wv = tid>>6, lane = tid&63, l15 = lane&15, quad = lane>>4;
    floatx4 acc[5][2];
    #pragma unroll
    for (int mt=0;mt<5;mt++){ acc[mt][0]=(floatx4){0,0,0,0}; acc[mt][1]=(floatx4){0,0,0,0}; }
    size_t hbase = (size_t)b*C_*NPAD;
    size_t wbase = (size_t)b*80*NPAD;
    for (int cidx=0; cidx<5; ++cidx){
        int n0c = blk*320 + cidx*64;
        #pragma unroll
        for (int i=0;i<3;i++){
            int idx = i*256 + tid;
            if (idx < 640){
                int row = idx>>3, seg = idx&7;
                uintx4 v = *(const uintx4*)&wBt[wbase + (size_t)row*NPAD + n0c + seg*8];
                *(uintx4*)&As[row*72 + seg*8] = v;
            }
        }
        #pragma unroll
        for (int i=0;i<4;i++){
            int idx = i*256 + tid;
            int row = idx>>3, seg = idx&7;
            int node = n0c + seg*8;
            uintx4 v = (uintx4){0,0,0,0};
            if (node < N_)
                v = *(const uintx4*)&hT[hbase + (size_t)row*NPAD + node];
            *(uintx4*)&Bs[row*72 + seg*8] = v;
        }
        __syncthreads();
        #pragma unroll
        for (int ks=0; ks<2; ks++){
            short8 bfrag[2];
            #pragma unroll
            for (int ot=0;ot<2;ot++)
                bfrag[ot] = *(const short8*)&Bs[(wv*32+ot*16+l15)*72 + ks*32 + quad*8];
            #pragma unroll
            for (int mt=0;mt<5;mt++){
                short8 af = *(const short8*)&As[(mt*16+l15)*72 + ks*32 + quad*8];
                acc[mt][0] = __builtin_amdgcn_mfma_f32_16x16x32_bf16(af, bfrag[0], acc[mt][0], 0,0,0);
                acc[mt][1] = __builtin_amdgcn_mfma_f32_16x16x32_bf16(af, bfrag[1], acc[mt][1], 0,0,0);
            }
        }
        __syncthreads();
    }
    float* pblk = part + ((size_t)(b*64+blk))*80*C_;
    #pragma unroll
    for (int mt=0;mt<5;mt++){
        #pragma unroll
        for (int ot=0;ot<2;ot++){
            int c = wv*32 + ot*16 + l15;
            #pragma unroll
            for (int r=0;r<4;r++){
                int kcol = mt*16 + quad*4 + r;
                pblk[kcol*C_ + c] = acc[mt][ot][r];
            }
        }
    }
}

__global__ __launch_bounds__(256) void reducePart_kernel(
    const float* __restrict__ part, float* __restrict__ xq)
{
    int idx = blockIdx.x*256 + threadIdx.x;
    if (idx >= B_*80*C_) return;
    int b = idx / (80*C_);
    int r = idx - b*80*C_;
    float s = 0.f;
    for (int blk=0; blk<64; blk++)
        s += part[((size_t)(b*64+blk))*80*C_ + r];
    xq[idx] = s;
}

// ---------------- per-layer: mode mixing (one block per o, 4 b-groups) ----------------

__global__ __launch_bounds__(256) void mix_kernel(
    const float* __restrict__ xq, const float* __restrict__ swc_l,
    const float* __restrict__ sws_l, const float* __restrict__ sw0_l,
    unsigned short* __restrict__ wfb, float* __restrict__ f0)
{
    __shared__ float s64[4][64];
    int o = blockIdx.x, tid = threadIdx.x;
    int b = tid >> 6, t = tid & 63;
    int k = t & 31; bool isS = t >= 32;
    const float* xqb = xq + (size_t)b*80*C_;
    float acc = 0.f;
    for (int c=0;c<C_;c++){
        float xc = xqb[k*C_ + c], xs = xqb[(32+k)*C_ + c];
        float wc = swc_l[((size_t)c*C_+o)*K_ + k];
        float ws = sws_l[((size_t)c*C_+o)*K_ + k];
        acc += isS ? (xs*wc + xc*ws) : (xc*wc - xs*ws);
    }
    wfb[((size_t)b*C_+o)*64 + t] = f2bf(isS ? -2.f*acc : 2.f*acc);
    float p = xqb[64*C_ + t]      * sw0_l[(size_t)t*C_+o]
            + xqb[64*C_ + 64 + t] * sw0_l[(size_t)(t+64)*C_+o];
    s64[b][t] = p; __syncthreads();
    if (t==0){
        float s=0.f;
        for (int i=0;i<64;i++) s += s64[b][i];
        f0[b*C_+o] = s;
    }
}

// ---------------- per-layer: gradient gather (packed CSR), XCD-swizzled ----------------
// epack[pos] = {src, w0, w1, w2}: one contiguous 16 B load per edge; only the
// h gather is a dependent (indirect) load.

__global__ __launch_bounds__(256) void grad_kernel(
    const unsigned short* __restrict__ hN, const uintx4* __restrict__ epack,
    const int* __restrict__ rowptr, unsigned short* __restrict__ g)
{
    int flat = blockIdx.x;              // 20000 blocks
    int xcd = flat & 7;
    int b = xcd >> 1;
    int grp = (flat >> 3)*2 + (xcd & 1);    // 0..4999 within batch
    int n = grp*4 + (threadIdx.x >> 6);
    int cp = threadIdx.x & 63;
    size_t bN = (size_t)b*N_;
    size_t bE = (size_t)b*E_;
    int r0 = rowptr[b*(N_+1)+n], r1 = rowptr[b*(N_+1)+n+1];
    unsigned int hcu = *(const unsigned int*)&hN[(bN+n)*C_ + cp*2];
    float hc0 = bf2f((unsigned short)hcu), hc1 = bf2f((unsigned short)(hcu>>16));
    float a00=0.f,a01=0.f,a02=0.f, a10=0.f,a11=0.f,a12=0.f;
    int i = r0;
    for (; i + 1 < r1; i += 2){
        uintx4 p0 = epack[bE + i];
        uintx4 p1 = epack[bE + i + 1];
        int s0 = (int)p0.x, s1 = (int)p1.x;
        unsigned int u0 = *(const unsigned int*)&hN[(bN+s0)*C_ + cp*2];
        unsigned int u1 = *(const unsigned int*)&hN[(bN+s1)*C_ + cp*2];
        float w00 = u2f(p0.y), w01 = u2f(p0.z), w02 = u2f(p0.w);
        float w10 = u2f(p1.y), w11 = u2f(p1.z), w12 = u2f(p1.w);
        float d00 = bf2f((unsigned short)u0) - hc0;
        float d01 = bf2f((unsigned short)(u0>>16)) - hc1;
        float d10 = bf2f((unsigned short)u1) - hc0;
        float d11 = bf2f((unsigned short)(u1>>16)) - hc1;
        a00 += w00*d00; a01 += w01*d00; a02 += w02*d00;
        a10 += w00*d01; a11 += w01*d01; a12 += w02*d01;
        a00 += w10*d10; a01 += w11*d10; a02 += w12*d10;
        a10 += w10*d11; a11 += w11*d11; a12 += w12*d11;
    }
    if (i < r1){
        uintx4 p0 = epack[bE + i];
        int s0 = (int)p0.x;
        unsigned int u0 = *(const unsigned int*)&hN[(bN+s0)*C_ + cp*2];
        float w00 = u2f(p0.y), w01 = u2f(p0.z), w02 = u2f(p0.w);
        float d00 = bf2f((unsigned short)u0) - hc0;
        float d01 = bf2f((unsigned short)(u0>>16)) - hc1;
        a00 += w00*d00; a01 += w01*d00; a02 += w02*d00;
        a10 += w00*d01; a11 += w01*d01; a12 += w02*d01;
    }
    unsigned short* gr = g + (bN+n)*(size_t)384 + cp*6;
    *(unsigned int*)(gr+0) = pack2(a00,a01);
    *(unsigned int*)(gr+2) = pack2(a02,a10);
    *(unsigned int*)(gr+4) = pack2(a11,a12);
}

// ---------------- per-layer: fused MFMA GEMM (K=576), R6 structure ----------------

__global__ __launch_bounds__(256) void gemm_kernel(
    const unsigned short* __restrict__ hN, const unsigned short* __restrict__ g,
    const unsigned short* __restrict__ bcb, const unsigned short* __restrict__ bsb,
    const unsigned short* __restrict__ wcat, const unsigned short* __restrict__ wfb,
    const float* __restrict__ wb_l, const float* __restrict__ gb_l,
    const float* __restrict__ f0,
    unsigned short* __restrict__ hNo, unsigned short* __restrict__ hT, int apply_gelu)
{
    __shared__ unsigned short As[2][64*72];
    int b = blockIdx.y;
    int nb0 = blockIdx.x*64;
    int tid = threadIdx.x;
    int a_n = tid>>2, a_s = tid&3;
    int wv = tid>>6, lane = tid&63, l15 = lane&15, quad = lane>>4;
    floatx4 acc[4][2];
    #pragma unroll
    for (int mt=0;mt<4;mt++)
        #pragma unroll
        for (int ot=0;ot<2;ot++) acc[mt][ot] = (floatx4){0.f,0.f,0.f,0.f};
    size_t bN = (size_t)b*N_;
    int gn = nb0 + a_n; bool av = gn < N_;
    size_t row = bN + (size_t)(av ? gn : 0);
    const unsigned short* hrow  = hN + row*C_;
    const unsigned short* grow  = g  + row*384;
    const unsigned short* bcrow = bcb + row*K_;
    const unsigned short* bsrow = bsb + row*K_;
    int o0 = wv*32 + l15, o1 = o0 + 16;
    const unsigned short* w0p = wcat + (size_t)o0*512 + quad*8;
    const unsigned short* w1p = wcat + (size_t)o1*512 + quad*8;
    const unsigned short* fb0 = wfb + ((size_t)b*C_ + o0)*64 + quad*8;
    const unsigned short* fb1 = wfb + ((size_t)b*C_ + o1)*64 + quad*8;

    auto loadA = [&](int ch, uintx4& v0, uintx4& v1){
        v0 = (uintx4){0,0,0,0}; v1 = (uintx4){0,0,0,0};
        if (av){
            if (ch < 8){
                const uintx4* p = (ch<2) ? (const uintx4*)(hrow + ch*64 + a_s*16)
                                         : (const uintx4*)(grow + (ch-2)*64 + a_s*16);
                v0 = p[0]; v1 = p[1];
            } else {
                const uintx4* p = (a_s < 2) ? (const uintx4*)(bcrow + a_s*16)
                                            : (const uintx4*)(bsrow + (a_s-2)*16);
                v0 = p[0]; v1 = p[1];
            }
        }
    };

    uintx4 c0, c1;
    loadA(0, c0, c1);
    *(uintx4*)&As[0][a_n*72 + a_s*16]     = c0;
    *(uintx4*)&As[0][a_n*72 + a_s*16 + 8] = c1;
    int p = 0;
    for (int ch=0; ch<9; ++ch){
        uintx4 n0v, n1v;
        if (ch < 8) loadA(ch+1, n0v, n1v);
        __syncthreads();
        #pragma unroll
        for (int ks=0; ks<2; ks++){
            short8 bfr0, bfr1;
            if (ch < 8){
                bfr0 = *(const short8*)(w0p + ch*64 + ks*32);
                bfr1 = *(const short8*)(w1p + ch*64 + ks*32);
            } else {
                bfr0 = *(const short8*)(fb0 + ks*32);
                bfr1 = *(const short8*)(fb1 + ks*32);
            }
            #pragma unroll
            for (int mt=0; mt<4; mt++){
                short8 af = *(const short8*)&As[p][(mt*16+l15)*72 + ks*32 + quad*8];
                acc[mt][0] = __builtin_amdgcn_mfma_f32_16x16x32_bf16(af, bfr0, acc[mt][0], 0,0,0);
                acc[mt][1] = __builtin_amdgcn_mfma_f32_16x16x32_bf16(af, bfr1, acc[mt][1], 0,0,0);
            }
        }
        if (ch < 8){
            *(uintx4*)&As[1-p][a_n*72 + a_s*16]     = n0v;
            *(uintx4*)&As[1-p][a_n*72 + a_s*16 + 8] = n1v;
            p ^= 1;
        }
    }
    float biasv[2]; int oo[2];
    oo[0]=o0; oo[1]=o1;
    #pragma unroll
    for (int ot=0;ot<2;ot++)
        biasv[ot] = wb_l[oo[ot]] + gb_l[oo[ot]] + f0[(size_t)b*C_ + oo[ot]];
    unsigned short* AsF = &As[0][0];   // reuse as [o][n] 128x72
    if (apply_gelu) __syncthreads();
    #pragma unroll
    for (int mt=0;mt<4;mt++){
        #pragma unroll
        for (int ot=0;ot<2;ot++){
            int nb = nb0 + mt*16 + quad*4;
            float v4[4];
            #pragma unroll
            for (int r=0;r<4;r++){
                float vv = acc[mt][ot][r] + biasv[ot];
                if (apply_gelu) vv = gelu_exact(vv);
                v4[r] = vv;
                if (nb + r < N_) hNo[(bN+nb+r)*C_ + oo[ot]] = f2bf(vv);
            }
            if (apply_gelu){
                uintx2 u; u.x = pack2(v4[0],v4[1]); u.y = pack2(v4[2],v4[3]);
                *(uintx2*)&AsF[oo[ot]*72 + mt*16 + quad*4] = u;
            }
        }
    }
    if (apply_gelu){
        __syncthreads();
        int orow = tid>>1, half = tid&1;
        uintx4 u0 = *(const uintx4*)&AsF[orow*72 + half*32];
        uintx4 u1 = *(const uintx4*)&AsF[orow*72 + half*32 + 8];
        unsigned short* dst = &hT[((size_t)b*C_ + orow)*NPAD + nb0 + half*32];
        *(uintx4*)dst       = u0;
        *(uintx4*)(dst + 8) = u1;
    }
}

// ---------------- head: MFMA fc1 + gelu + fc2 ----------------

__global__ __launch_bounds__(256) void final_kernel(
    const unsigned short* __restrict__ hN, const unsigned short* __restrict__ fc1b16,
    const float* __restrict__ fc1b, const float* __restrict__ fc2w,
    const float* __restrict__ fc2b, float* __restrict__ out)
{
    __shared__ unsigned short As[64*72];
    __shared__ float pp[4*64];
    int b = blockIdx.y;
    int nb0 = blockIdx.x*64;
    int tid = threadIdx.x;
    int a_n = tid>>2, a_s = tid&3;
    int wv = tid>>6, lane = tid&63, l15 = lane&15, quad = lane>>4;
    floatx4 acc[4][2];
    #pragma unroll
    for (int mt=0;mt<4;mt++){ acc[mt][0]=(floatx4){0,0,0,0}; acc[mt][1]=(floatx4){0,0,0,0}; }
    size_t bN = (size_t)b*N_;
    int gn = nb0 + a_n; bool av = gn < N_;
    size_t row = bN + (size_t)(av ? gn : 0);
    const unsigned short* hrow = hN + row*C_;
    int o0 = wv*32 + l15, o1 = o0 + 16;
    const unsigned short* w0p = fc1b16 + (size_t)o0*C_ + quad*8;
    const unsigned short* w1p = fc1b16 + (size_t)o1*C_ + quad*8;

    for (int ch=0; ch<2; ++ch){
        uintx4 v0 = (uintx4){0,0,0,0}, v1 = (uintx4){0,0,0,0};
        if (av){
            const uintx4* pptr = (const uintx4*)(hrow + ch*64 + a_s*16);
            v0 = pptr[0]; v1 = pptr[1];
        }
        *(uintx4*)&As[a_n*72 + a_s*16]     = v0;
        *(uintx4*)&As[a_n*72 + a_s*16 + 8] = v1;
        __syncthreads();
        #pragma unroll
        for (int ks=0; ks<2; ks++){
            short8 bfr0 = *(const short8*)(w0p + ch*64 + ks*32);
            short8 bfr1 = *(const short8*)(w1p + ch*64 + ks*32);
            #pragma unroll
            for (int mt=0; mt<4; mt++){
                short8 af = *(const short8*)&As[(mt*16+l15)*72 + ks*32 + quad*8];
                acc[mt][0] = __builtin_amdgcn_mfma_f32_16x16x32_bf16(af, bfr0, acc[mt][0], 0,0,0);
                acc[mt][1] = __builtin_amdgcn_mfma_f32_16x16x32_bf16(af, bfr1, acc[mt][1], 0,0,0);
            }
        }
        __syncthreads();
    }
    float fw0 = fc2w[o0], fw1 = fc2w[o1];
    float b0 = fc1b[o0], b1 = fc1b[o1];
    #pragma unroll
    for (int mt=0;mt<4;mt++){
        float s[4];
        #pragma unroll
        for (int r=0;r<4;r++)
            s[r] = fw0*gelu_exact(acc[mt][0][r] + b0) + fw1*gelu_exact(acc[mt][1][r] + b1);
        #pragma unroll
        for (int m=1;m<16;m<<=1)
            #pragma unroll
            for (int r=0;r<4;r++)
                s[r] += __shfl_xor(s[r], m, 16);
        if (l15 < 4){
            float v = (l15==0)?s[0]:(l15==1)?s[1]:(l15==2)?s[2]:s[3];
            pp[wv*64 + mt*16 + quad*4 + l15] = v;
        }
    }
    __syncthreads();
    if (tid < 64){
        float sum = pp[tid] + pp[64+tid] + pp[128+tid] + pp[192+tid] + fc2b[0];
        int n = nb0 + tid;
        if (n < N_) out[bN + n] = sum;
    }
}

// ---------------- launch ----------------

extern "C" void kernel_launch(void* const* d_in, const int* in_sizes, int n_in,
                              void* d_out, int out_size, void* d_ws, size_t ws_size,
                              hipStream_t stream)
{
    const float* x      = (const float*)d_in[0];
    const float* nodes  = (const float*)d_in[2];
    const float* nw     = (const float*)d_in[3];
    const int*   edges  = (const int*)  d_in[4];
    const float* egw    = (const float*)d_in[5];
    const float* modes  = (const float*)d_in[6];
    const float* latent = (const float*)d_in[7];
    const float* fc0w   = (const float*)d_in[8];
    const float* fc0b   = (const float*)d_in[9];
    const float* swc    = (const float*)d_in[10];
    const float* sws    = (const float*)d_in[11];
    const float* sw0    = (const float*)d_in[12];
    const float* ww     = (const float*)d_in[13];
    const float* wb     = (const float*)d_in[14];
    const float* gw     = (const float*)d_in[15];
    const float* gb     = (const float*)d_in[16];
    const float* fc1w   = (const float*)d_in[17];
    const float* fc1b   = (const float*)d_in[18];
    const float* fc2w   = (const float*)d_in[19];
    const float* fc2b   = (const float*)d_in[20];
    float* out = (float*)d_out;

    char* W = (char*)d_ws;
    size_t off = 0;
    unsigned short* bcB = (unsigned short*)(W+off); off += (size_t)NROWS*K_*2;
    unsigned short* bsB = (unsigned short*)(W+off); off += (size_t)NROWS*K_*2;
    unsigned short* wBt = (unsigned short*)(W+off); off += (size_t)B_*80*NPAD*2;
    unsigned short* hT  = (unsigned short*)(W+off); off += (size_t)B_*C_*NPAD*2;
    unsigned short* hNa = (unsigned short*)(W+off); off += (size_t)NROWS*C_*2;
    unsigned short* hNb = (unsigned short*)(W+off); off += (size_t)NROWS*C_*2;
    unsigned short* g   = (unsigned short*)(W+off); off += (size_t)NROWS*C_*3*2;
    unsigned short* wcat3=(unsigned short*)(W+off); off += (size_t)3*C_*512*2;
    unsigned short* wfb = (unsigned short*)(W+off); off += (size_t)B_*C_*64*2;
    unsigned short* fcw16=(unsigned short*)(W+off); off += (size_t)C_*C_*2;
    float* part = (float*)(W+off); off += (size_t)B_*64*80*C_*4;
    float* xq   = (float*)(W+off); off += (size_t)B_*80*C_*4;
    float* f0   = (float*)(W+off); off += (size_t)B_*C_*4;
    off = (off + 15) & ~(size_t)15;
    uintx4* epack = (uintx4*)(W+off); off += (size_t)B_*E_*16;
    int* cnt    = (int*)(W+off); off += (size_t)B_*N_*4;
    int* rowptr = (int*)(W+off); off += (size_t)B_*(N_+1)*4 + 16;
    int* cur    = (int*)(W+off); off += (size_t)B_*N_*4;

    (void)hipMemsetAsync(cnt, 0, (size_t)B_*N_*sizeof(int), stream);
    basis_kernel<<<dim3(NPAD/64, B_), 256, 0, stream>>>(
        nodes, nw, modes, latent, bcB, bsB, wBt);
    fc0_kernel  <<<(B_*N_+255)/256, 256, 0, stream>>>(x, fc0w, fc0b, hNa, hT);
    hist_kernel <<<(B_*E_+255)/256, 256, 0, stream>>>(edges, cnt);
    scan_kernel <<<B_, 1024, 0, stream>>>(cnt, rowptr, cur);
    fill_kernel <<<(B_*E_+255)/256, 256, 0, stream>>>(edges, egw, cur, epack);
    wconv_kernel<<<dim3(C_,3), 256, 0, stream>>>(ww, gw, wcat3);
    fc1conv_kernel<<<C_, 64, 0, stream>>>(fc1w, fcw16);

    unsigned short* hc = hNa; unsigned short* hn = hNb;
    for (int l=0; l<3; ++l){
        stageA_kernel<<<dim3(64,B_), 256, 0, stream>>>(hT, wBt, part);
        reducePart_kernel<<<(B_*80*C_+255)/256, 256, 0, stream>>>(part, xq);
        mix_kernel<<<C_, 256, 0, stream>>>(
            xq, swc + (size_t)l*C_*C_*K_, sws + (size_t)l*C_*C_*K_,
            sw0 + (size_t)l*C_*C_, wfb, f0);
        grad_kernel<<<N_, 256, 0, stream>>>(hc, epack, rowptr, g);
        gemm_kernel<<<dim3((N_+63)/64,B_), 256, 0, stream>>>(
            hc, g, bcB, bsB, wcat3 + (size_t)l*C_*512, wfb,
            wb + (size_t)l*C_, gb + (size_t)l*C_,
            f0, hn, hT, (l<2) ? 1 : 0);
        unsigned short* t = hc; hc = hn; hn = t;
    }
    final_kernel<<<dim3((N_+63)/64,B_), 256, 0, stream>>>(
        hc, fcw16, fc1b, fc2w, fc2b, out);
}